// Round 17
// baseline (5679.606 us; speedup 1.0000x reference)
//
#include <hip/hip_runtime.h>
#include <stdint.h>

typedef _Float16 f16;
typedef f16  f16x8 __attribute__((ext_vector_type(8)));
typedef float f32x4 __attribute__((ext_vector_type(4)));
typedef unsigned u32x2 __attribute__((ext_vector_type(2)));
typedef unsigned u32x4 __attribute__((ext_vector_type(4)));

// ---------------- ws layout (byte offsets) ----------------
// H0/H1: 2 bufs x [k/8][b][8] f16 (fp16 h, 512KB per buf region incl both bufs 1MB)
// WHH0F: fp16 MFMA A-frags of Whh0, [hgrp256][frag32][lane64][8] = 8 MB
// SEQ [84][256] f32 | YACC [24][256] f32 | FLAG 2 halves x (256+16) x 128B
#define H0_OFF    0u
#define H1_OFF    2097152u
#define WHH0F_OFF 4194304u
#define SEQ_OFF   12582912u
#define YACC_OFF  12668928u
#define FLAG_OFF  12693504u

__device__ __forceinline__ unsigned rotl32(unsigned x, int d){ return (x<<d)|(x>>(32-d)); }

// Threefry-2x32, 20 rounds, exactly JAX's key schedule. (bit-exact, proven R1-R16)
__device__ __forceinline__ uint2 tf2x32(unsigned k0, unsigned k1, unsigned x0, unsigned x1){
  unsigned kx = k0 ^ k1 ^ 0x1BD11BDAu;
  x0 += k0; x1 += k1;
#define TFR(r) { x0 += x1; x1 = rotl32(x1,(r)); x1 ^= x0; }
  TFR(13) TFR(15) TFR(26) TFR(6)  x0 += k1; x1 += kx + 1u;
  TFR(17) TFR(29) TFR(16) TFR(24) x0 += kx; x1 += k0 + 2u;
  TFR(13) TFR(15) TFR(26) TFR(6)  x0 += k0; x1 += k1 + 3u;
  TFR(17) TFR(29) TFR(16) TFR(24) x0 += k1; x1 += kx + 4u;
  TFR(13) TFR(15) TFR(26) TFR(6)  x0 += kx; x1 += k0 + 5u;
#undef TFR
  return make_uint2(x0, x1);
}

__device__ __forceinline__ bool drop_keep(uint2 fk, unsigned n){
  uint2 o = tf2x32(fk.x, fk.y, 0u, n);
  unsigned bits = o.x ^ o.y;
  float u = __uint_as_float((bits >> 9) | 0x3f800000u) - 1.0f;
  return u < 0.8f;
}

__device__ __forceinline__ float sigf(float x){ return 1.0f/(1.0f + __expf(-x)); }
__device__ __forceinline__ float thf(float x){ return 1.0f - 2.0f/(__expf(2.0f*x) + 1.0f); }

// ---- LLC-coherent accessors (proven R4-R16) ----
__device__ __forceinline__ void st_dword_sc(void* p, unsigned v){
  asm volatile("global_store_dword %0, %1, off sc0 sc1" :: "v"(p), "v"(v) : "memory");
}
__device__ __forceinline__ void st_dwordx2_sc(void* p, u32x2 v){
  asm volatile("global_store_dwordx2 %0, %1, off sc0 sc1" :: "v"(p), "v"(v) : "memory");
}
__device__ __forceinline__ unsigned ld_dword_sc(const void* p){
  unsigned r;
  asm volatile("global_load_dword %0, %1, off sc0 sc1\n\ts_waitcnt vmcnt(0)"
               : "=v"(r) : "v"(p) : "memory");
  return r;
}

// Per-half 2-level tree barrier: 256 blocks, 16 leaders x 16 flags; inv optional.
__device__ __forceinline__ void gbar(unsigned* flagsH, unsigned* gflagsH, unsigned e,
                                     int tid, int lblk, bool inv){
  asm volatile("s_waitcnt vmcnt(0)" ::: "memory");
  __syncthreads();
  if (tid == 0) st_dword_sc(flagsH + lblk*32, e);
  if (lblk < 16){
    if (tid < 16){
      unsigned* f = flagsH + (lblk*16 + tid)*32;
      while (ld_dword_sc(f) < e) __builtin_amdgcn_s_sleep(1);
    }
    __syncthreads();
    if (tid == 0) st_dword_sc(gflagsH + lblk*32, e);
  }
  if (tid < 16){
    unsigned* f = gflagsH + tid*32;
    while (ld_dword_sc(f) < e) __builtin_amdgcn_s_sleep(1);
  }
  __syncthreads();
  if (inv) __builtin_amdgcn_fence(__ATOMIC_ACQUIRE, "agent");
  __builtin_amdgcn_sched_barrier(0);
}

// ---- prep: zero h buffers + y_acc + flags ----
__global__ void k_init(uint4* __restrict__ hz, uint4* __restrict__ yz, uint4* __restrict__ fz){
  unsigned i = blockIdx.x*256u + threadIdx.x;
  if (i < 262144u){ hz[i] = uint4{0,0,0,0}; }
  else if (i < 263680u){ yz[i - 262144u] = uint4{0,0,0,0}; }
  else if (i < 268032u){ fz[i - 263680u] = uint4{0,0,0,0}; }
}

// ---- prep: conv1d(pad1,k3) + relu + maxpool2 -> seq[84][256] ----
__global__ void k_seq(const float* __restrict__ x, const float* __restrict__ cw,
                      const float* __restrict__ cb, float* __restrict__ seq){
  const int q = blockIdx.x;
  const int b = threadIdx.x;
  float best = -1e30f;
#pragma unroll
  for (int ssub = 0; ssub < 2; ++ssub){
    int p = 2*q + ssub;
    float acc = cb[0];
#pragma unroll
    for (int k = 0; k < 3; ++k){
      int t = p - 1 + k;
      if (t >= 0 && t < 168){
        const float* xp = x + ((size_t)b*192 + t)*8;
#pragma unroll
        for (int i = 0; i < 8; ++i) acc = fmaf(xp[i], cw[i*3 + k], acc);
      }
    }
    acc  = fmaxf(acc, 0.0f);
    best = fmaxf(best, acc);
  }
  seq[(q<<8) + b] = best;
}

// ---- prep: pack Whh0 into fp16 MFMA A-frags, U=4 per hgrp (256 hgrps) ----
// frag c (0..31): lane l, half j -> W[(g<<10)+j0+u][c*32+(l>>4)*8+j], r=l&15, u=r>>2, g=r&3
__global__ void __launch_bounds__(512) k_wpack(const float* __restrict__ W, f16* __restrict__ dst){
  const int hgrp = blockIdx.x;       // 0..255
  const int tid = threadIdx.x;
  const int l   = tid & 63;
  const int w   = tid >> 6;          // 0..7
  const int j0  = hgrp << 2;
#pragma unroll
  for (int fi = 0; fi < 4; ++fi){
    const int f = (w << 2) + fi;     // 0..31
    const int r = l & 15;
    const int u = r >> 2;
    const int g = r & 3;
    const float* src = W + (((size_t)((g << 10) + j0 + u)) << 10) + (f << 5) + ((l >> 4) << 3);
    float4 a = *(const float4*)src;
    float4 b = *(const float4*)(src + 4);
    f16x8 v;
    v[0]=(f16)a.x; v[1]=(f16)a.y; v[2]=(f16)a.z; v[3]=(f16)a.w;
    v[4]=(f16)b.x; v[5]=(f16)b.y; v[6]=(f16)b.z; v[7]=(f16)b.w;
    *(f16x8*)(dst + ((size_t)hgrp << 14) + (f << 9) + (l << 3)) = v;
  }
}

#define MFMA16(a,b,c) __builtin_amdgcn_mfma_f32_16x16x32_f16((a),(b),(c),0,0,0)

// ---- main: 512 blocks (256 hgrp x 2 bgrp) x 512 threads, 2 blocks/CU ----
// LDS (halves): Wih1 [0,16384) | Whh1 [16384,32768) | stage [32768,33280) |
//               wstage [33280,37376) = 74752 B total (<= 80KB -> 2 blocks/CU)
__global__ void __launch_bounds__(512, 4) k_main(
    const float* __restrict__ Wih0, const float* __restrict__ Whh0,
    const float* __restrict__ bih0, const float* __restrict__ bhh0,
    const float* __restrict__ Wih1, const float* __restrict__ Whh1,
    const float* __restrict__ bih1, const float* __restrict__ bhh1,
    const float* __restrict__ fc_w, const float* __restrict__ fc_b,
    char* __restrict__ ws, float* __restrict__ out)
{
  extern __shared__ char smem_[];
  f16* lds    = (f16*)smem_;
  f16* stage  = lds + 32768;       // 512 halves: [128 cols][4 units]
  f16* wstage = lds + 33280;       // 2 bufs x 2048 halves (whh0f chunk staging)

  const int tid  = threadIdx.x;
  const int blk  = blockIdx.x;
  const int hgrp = blk & 255;      // hidden units 4*hgrp..+3
  const int bgrp = blk >> 8;       // batch cols bgrp*128..+127
  const int j0   = hgrp << 2;
  const int l    = tid & 63;
  const int w8   = tid >> 6;       // wave 0..7, local cols w8*16..+16
  const int q    = l >> 4;         // k-subgroup AND unit index (lane-group q owns unit j0+q)
  const int c16  = l & 15;
  const int lcol = (w8 << 4) + c16;
  const int bcol = (bgrp << 7) + lcol;

  // ---- pack Wih1, Whh1 slices into LDS as MFMA A-frags (once) ----
  {
    const float* srcs[2] = {Wih1, Whh1};
#pragma unroll
    for (int m = 0; m < 2; ++m){
#pragma unroll
      for (int fi = 0; fi < 4; ++fi){
        const int f = (w8 << 2) + fi;      // 0..31
        const int r = c16;
        const int uu = r >> 2;
        const int g = r & 3;
        const float* src = srcs[m] + (((size_t)((g << 10) + j0 + uu)) << 10) + (f << 5) + (q << 3);
        float4 a = *(const float4*)src;
        float4 b = *(const float4*)(src + 4);
        f16x8 v;
        v[0]=(f16)a.x; v[1]=(f16)a.y; v[2]=(f16)a.z; v[3]=(f16)a.w;
        v[4]=(f16)b.x; v[5]=(f16)b.y; v[6]=(f16)b.z; v[7]=(f16)b.w;
        *(f16x8*)(lds + m*16384 + (f << 9) + (l << 3)) = v;
      }
    }
  }
  __syncthreads();

  // ---- per-lane constants (single unit j0+q; gates g=0..3 = acc[0..3]) ----
  float bias0g[4], bias1g[4], wi0g[4];
#pragma unroll
  for (int g = 0; g < 4; ++g){
    int row = (g << 10) + j0 + q;
    bias0g[g] = bih0[row] + bhh0[row];
    bias1g[g] = bih1[row] + bhh1[row];
    wi0g[g]   = Wih0[row];
  }
  const float fcwq = fc_w[j0 + q] * 1.25f;
  const float fcb  = fc_b[0];

  const int base_h = (q << 11) + (bcol << 3);   // per-lane B-frag offset (halves)

  f16* H0 = (f16*)(ws + H0_OFF);   // per-buf 262144 halves (fp16)
  f16* H1 = (f16*)(ws + H1_OFF);
  const f16* whh0f = (const f16*)(ws + WHH0F_OFF) + ((size_t)hgrp << 14);
  const float* seq = (const float*)(ws + SEQ_OFF);
  float* y_acc = (float*)(ws + YACC_OFF);
  unsigned* flagsH  = (unsigned*)(ws + FLAG_OFF) + bgrp*8704;   // 256 flags + 16 gflags
  unsigned* gflagsH = flagsH + 256*32;

  // h-publication address (8B per col: this block's 4 units within a k-octet)
  const int puboff = ((hgrp >> 1) << 11) + ((hgrp & 1) << 2);   // halves

  // ---- whh0f resident in 16 VGPRs (8 chunks x 8B/thread) ----
  u32x2 wreg[8];
#pragma unroll
  for (int ch = 0; ch < 8; ++ch)
    wreg[ch] = *(const u32x2*)(whh0f + (ch << 11) + (tid << 2));

  // ---- rolling prefetch of phase-A h groups (crosses barriers) ----
  f16x8 BhP[2][4];
  {
    const f16* a00 = H0 + base_h;
#pragma unroll
    for (int i = 0; i < 4; ++i){
      BhP[0][i] = *(const f16x8*)(a00 + i*8192);
      BhP[1][i] = *(const f16x8*)(a00 + (4+i)*8192);
    }
  }

  float c0 = 0.f, c1 = 0.f, yprev = 0.f;
  unsigned ep = 0;

#pragma unroll 1
  for (int s = 0; s < 107; ++s){
    const int src = s & 1, dst = src ^ 1;

    if (s >= 84){
      const int tp = s - 84;
      yprev = fcb + __uint_as_float(ld_dword_sc(y_acc + (tp << 8) + bcol));
      if (hgrp == 0 && q == 0) out[bcol*24 + tp] = yprev;
    }

    // ========= phase A: gates0 = Whh0*h0 (weights regs->LDS chunks, 32 MFMA) =========
    float h0n;
    {
      const f16* a0 = H0 + src*262144 + base_h;
      f32x4 acc = (f32x4){0,0,0,0};
      *(u32x2*)(wstage + (tid << 2)) = wreg[0];
      __syncthreads();
#define LDH(B, C0) { _Pragma("unroll") for (int i = 0; i < 4; ++i){ \
      BhP[B][i] = *(const f16x8*)(a0 + ((C0)+i)*8192); } }
#define MMW(B, CH) { const f16* wsb = wstage + (((CH)&1) << 11) + (l << 3); \
      _Pragma("unroll") for (int i = 0; i < 4; ++i){ \
      f16x8 wf = *(const f16x8*)(wsb + (i << 9)); \
      acc = MFMA16(wf, BhP[B][i], acc); } }
#pragma unroll
      for (int ch = 0; ch < 8; ++ch){
        if (ch < 7) *(u32x2*)(wstage + (((ch+1)&1) << 11) + (tid << 2)) = wreg[ch+1];
        MMW(ch&1, ch)
        if (ch < 6) LDH(ch&1, (ch+2)*4)
        if (ch < 7) __syncthreads();
      }
#undef LDH
#undef MMW
      float xb = (s < 84) ? seq[(s << 8) + bcol] : yprev;
      float pi = acc[0] + bias0g[0] + wi0g[0]*xb;
      float pf = acc[1] + bias0g[1] + wi0g[1]*xb;
      float pg = acc[2] + bias0g[2] + wi0g[2]*xb;
      float po = acc[3] + bias0g[3] + wi0g[3]*xb;
      c0  = sigf(pf)*c0 + sigf(pi)*thf(pg);
      h0n = sigf(po)*thf(c0);
      stage[(lcol << 2) + q] = (f16)h0n;
    }
    __syncthreads();
    if (tid < 128){
      u32x2 v = ((const u32x2*)stage)[tid];
      st_dwordx2_sc((char*)(H0 + dst*262144 + puboff + (((bgrp << 7) + tid) << 3)) , v);
    }
    ++ep; gbar(flagsH, gflagsH, ep, tid, hgrp, true);   // mid barrier WITH inv

    // ========= phase B: gates1 = Wih1*h0new + Whh1*h1 (LDS weights, 64 MFMA) =========
    float h1n;
    {
      const f16* b0 = H0 + dst*262144 + base_h;
      const f16* b1 = H1 + src*262144 + base_h;
      f16x8 X0[2][4], X1[2][4];
      f32x4 acc = (f32x4){0,0,0,0};
#define LDB(B, CB) { _Pragma("unroll") for (int i = 0; i < 4; ++i){ const int c = (CB)+i; \
      X0[B][i] = *(const f16x8*)(b0 + c*8192); \
      X1[B][i] = *(const f16x8*)(b1 + c*8192); } }
#define MMB(B, CB) { _Pragma("unroll") for (int i = 0; i < 4; ++i){ const int c = (CB)+i; \
      f16x8 wa = *(const f16x8*)(lds + (c << 9) + (l << 3)); \
      f16x8 wb = *(const f16x8*)(lds + 16384 + (c << 9) + (l << 3)); \
      acc = MFMA16(wa, X0[B][i], acc); \
      acc = MFMA16(wb, X1[B][i], acc); } }
      LDB(0, 0)
#pragma unroll
      for (int cb = 0; cb < 8; ++cb){
        if ((cb & 1) == 0){ if (cb < 7) LDB(1, (cb+1)*4) MMB(0, cb*4) }
        else              { if (cb < 7) LDB(0, (cb+1)*4) MMB(1, cb*4) }
      }
#undef LDB
#undef MMB
      float pi = acc[0] + bias1g[0];
      float pf = acc[1] + bias1g[1];
      float pg = acc[2] + bias1g[2];
      float po = acc[3] + bias1g[3];
      c1  = sigf(pf)*c1 + sigf(pi)*thf(pg);
      h1n = sigf(po)*thf(c1);
      stage[(lcol << 2) + q] = (f16)h1n;
    }
    __syncthreads();
    if (tid < 128){
      u32x2 v = ((const u32x2*)stage)[tid];
      st_dwordx2_sc((char*)(H1 + dst*262144 + puboff + (((bgrp << 7) + tid) << 3)) , v);
    }
    __syncthreads();   // protect stage from next phase-A overwrite

    // ---- prefetch next step's phase-A h groups 0,1 (final + L2-fresh here) ----
    {
      const f16* a0n = H0 + dst*262144 + base_h;
#pragma unroll
      for (int i = 0; i < 4; ++i){
        BhP[0][i] = *(const f16x8*)(a0n + i*8192);
        BhP[1][i] = *(const f16x8*)(a0n + (4+i)*8192);
      }
    }

    // ---- fc partials with exact JAX dropout (tau = s-83) ----
    if (s >= 83){
      const int tau = s - 83;
      uint2 fk = tf2x32(0u, 42u, 0u, (unsigned)tau);
      unsigned n = ((unsigned)bcol << 10) + (unsigned)(j0 + q);
      float v = drop_keep(fk, n) ? h1n*fcwq : 0.f;
      v += __shfl_xor(v, 16, 64);
      v += __shfl_xor(v, 32, 64);
      if (q == 0) atomicAdd(y_acc + (tau << 8) + bcol, v);
      ++ep; gbar(flagsH, gflagsH, ep, tid, hgrp, false);  // end barrier, NO inv
    }
  }

  // tail: y_23 (LLC-coherent read)
  if (hgrp == 0 && q == 0)
    out[bcol*24 + 23] = fcb + __uint_as_float(ld_dword_sc(y_acc + (23 << 8) + bcol));
}

extern "C" void kernel_launch(void* const* d_in, const int* in_sizes, int n_in,
                              void* d_out, int out_size, void* d_ws, size_t ws_size,
                              hipStream_t stream)
{
  const float* x    = (const float*)d_in[0];
  const float* cw   = (const float*)d_in[1];
  const float* cb   = (const float*)d_in[2];
  const float* Wih0 = (const float*)d_in[3];
  const float* Whh0 = (const float*)d_in[4];
  const float* bih0 = (const float*)d_in[5];
  const float* bhh0 = (const float*)d_in[6];
  const float* Wih1 = (const float*)d_in[7];
  const float* Whh1 = (const float*)d_in[8];
  const float* bih1 = (const float*)d_in[9];
  const float* bhh1 = (const float*)d_in[10];
  const float* fc_w = (const float*)d_in[11];
  const float* fc_b = (const float*)d_in[12];
  float* out = (float*)d_out;
  char*  ws  = (char*)d_ws;

  hipLaunchKernelGGL(k_init, dim3(1047), dim3(256), 0, stream,
                     (uint4*)(ws + H0_OFF), (uint4*)(ws + YACC_OFF), (uint4*)(ws + FLAG_OFF));
  hipLaunchKernelGGL(k_seq,  dim3(84), dim3(256), 0, stream, x, cw, cb, (float*)(ws + SEQ_OFF));
  hipLaunchKernelGGL(k_wpack, dim3(256), dim3(512), 0, stream, Whh0, (f16*)(ws + WHH0F_OFF));
  hipLaunchKernelGGL(k_main, dim3(512), dim3(512), 74752, stream,
                     Wih0, Whh0, bih0, bhh0, Wih1, Whh1, bih1, bhh1,
                     fc_w, fc_b, ws, out);
}

// Round 18
// 3259.325 us; speedup vs baseline: 1.7426x; 1.7426x over previous
//
#include <hip/hip_runtime.h>
#include <stdint.h>

typedef _Float16 f16;
typedef f16  f16x8 __attribute__((ext_vector_type(8)));
typedef float f32x4 __attribute__((ext_vector_type(4)));
typedef unsigned u32x4 __attribute__((ext_vector_type(4)));

// ---------------- ws layout (byte offsets) ----------------
// H0/H1: 2 bufs x [k/8][b][8] f16 (fp16-only h, 512KB per buf)
// WHH0F: fp16 MFMA A-frags of Whh0, [hgrp128][frag64][lane64][8] = 8 MB
// SEQ [84][256] f32 | YACC [24][256] f32 | FLAG 2 halves x (128+8) x 128B
#define H0_OFF    0u
#define H1_OFF    2097152u
#define WHH0F_OFF 4194304u
#define SEQ_OFF   12582912u
#define YACC_OFF  12668928u
#define FLAG_OFF  12693504u

__device__ __forceinline__ unsigned rotl32(unsigned x, int d){ return (x<<d)|(x>>(32-d)); }

// Threefry-2x32, 20 rounds, exactly JAX's key schedule. (bit-exact, proven R1-R17)
__device__ __forceinline__ uint2 tf2x32(unsigned k0, unsigned k1, unsigned x0, unsigned x1){
  unsigned kx = k0 ^ k1 ^ 0x1BD11BDAu;
  x0 += k0; x1 += k1;
#define TFR(r) { x0 += x1; x1 = rotl32(x1,(r)); x1 ^= x0; }
  TFR(13) TFR(15) TFR(26) TFR(6)  x0 += k1; x1 += kx + 1u;
  TFR(17) TFR(29) TFR(16) TFR(24) x0 += kx; x1 += k0 + 2u;
  TFR(13) TFR(15) TFR(26) TFR(6)  x0 += k0; x1 += k1 + 3u;
  TFR(17) TFR(29) TFR(16) TFR(24) x0 += k1; x1 += kx + 4u;
  TFR(13) TFR(15) TFR(26) TFR(6)  x0 += kx; x1 += k0 + 5u;
#undef TFR
  return make_uint2(x0, x1);
}

__device__ __forceinline__ bool drop_keep(uint2 fk, unsigned n){
  uint2 o = tf2x32(fk.x, fk.y, 0u, n);
  unsigned bits = o.x ^ o.y;
  float u = __uint_as_float((bits >> 9) | 0x3f800000u) - 1.0f;
  return u < 0.8f;
}

__device__ __forceinline__ float sigf(float x){ return 1.0f/(1.0f + __expf(-x)); }
__device__ __forceinline__ float thf(float x){ return 1.0f - 2.0f/(__expf(2.0f*x) + 1.0f); }

// ---- LLC-coherent accessors (proven R4-R16) ----
__device__ __forceinline__ void st_dword_sc(void* p, unsigned v){
  asm volatile("global_store_dword %0, %1, off sc0 sc1" :: "v"(p), "v"(v) : "memory");
}
__device__ __forceinline__ void st_dwordx4_sc(void* p, u32x4 v){
  asm volatile("global_store_dwordx4 %0, %1, off sc0 sc1" :: "v"(p), "v"(v) : "memory");
}
__device__ __forceinline__ unsigned ld_dword_sc(const void* p){
  unsigned r;
  asm volatile("global_load_dword %0, %1, off sc0 sc1\n\ts_waitcnt vmcnt(0)"
               : "=v"(r) : "v"(p) : "memory");
  return r;
}

// Per-half 2-level tree barrier: 128 blocks, 8 leaders x 16 flags; inv optional.
__device__ __forceinline__ void gbar(unsigned* flagsH, unsigned* gflagsH, unsigned e,
                                     int tid, int lblk, bool inv){
  asm volatile("s_waitcnt vmcnt(0)" ::: "memory");
  __syncthreads();
  if (tid == 0) st_dword_sc(flagsH + lblk*32, e);
  if (lblk < 8){
    if (tid < 16){
      unsigned* f = flagsH + (lblk*16 + tid)*32;
      while (ld_dword_sc(f) < e) __builtin_amdgcn_s_sleep(1);
    }
    __syncthreads();
    if (tid == 0) st_dword_sc(gflagsH + lblk*32, e);
  }
  if (tid < 8){
    unsigned* f = gflagsH + tid*32;
    while (ld_dword_sc(f) < e) __builtin_amdgcn_s_sleep(1);
  }
  __syncthreads();
  if (inv) __builtin_amdgcn_fence(__ATOMIC_ACQUIRE, "agent");
  __builtin_amdgcn_sched_barrier(0);
}

// ---- prep: zero h buffers + y_acc + flags ----
__global__ void k_init(uint4* __restrict__ hz, uint4* __restrict__ yz, uint4* __restrict__ fz){
  unsigned i = blockIdx.x*256u + threadIdx.x;
  if (i < 262144u){ hz[i] = uint4{0,0,0,0}; }
  else if (i < 263680u){ yz[i - 262144u] = uint4{0,0,0,0}; }
  else if (i < 265856u){ fz[i - 263680u] = uint4{0,0,0,0}; }
}

// ---- prep: conv1d(pad1,k3) + relu + maxpool2 -> seq[84][256] ----
__global__ void k_seq(const float* __restrict__ x, const float* __restrict__ cw,
                      const float* __restrict__ cb, float* __restrict__ seq){
  const int q = blockIdx.x;
  const int b = threadIdx.x;
  float best = -1e30f;
#pragma unroll
  for (int ssub = 0; ssub < 2; ++ssub){
    int p = 2*q + ssub;
    float acc = cb[0];
#pragma unroll
    for (int k = 0; k < 3; ++k){
      int t = p - 1 + k;
      if (t >= 0 && t < 168){
        const float* xp = x + ((size_t)b*192 + t)*8;
#pragma unroll
        for (int i = 0; i < 8; ++i) acc = fmaf(xp[i], cw[i*3 + k], acc);
      }
    }
    acc  = fmaxf(acc, 0.0f);
    best = fmaxf(best, acc);
  }
  seq[(q<<8) + b] = best;
}

// ---- prep: pack Whh0 (fp32 [4096][1024]) into fp16 MFMA A-frags per hgrp ----
__global__ void __launch_bounds__(512) k_wpack(const float* __restrict__ W, f16* __restrict__ dst){
  const int hgrp = blockIdx.x;       // 0..127
  const int tid = threadIdx.x;
  const int l   = tid & 63;
  const int w   = tid >> 6;          // 0..7
  const int j0  = hgrp << 3;
#pragma unroll
  for (int fi = 0; fi < 8; ++fi){
    const int f = (w << 3) + fi;     // 0..63
    const int c = f >> 1, T = f & 1;
    const int r = l & 15;
    const int u = (T << 2) + (r >> 2);
    const int g = r & 3;
    const float* src = W + (((size_t)((g << 10) + j0 + u)) << 10) + (c << 5) + ((l >> 4) << 3);
    float4 a = *(const float4*)src;
    float4 b = *(const float4*)(src + 4);
    f16x8 v;
    v[0]=(f16)a.x; v[1]=(f16)a.y; v[2]=(f16)a.z; v[3]=(f16)a.w;
    v[4]=(f16)b.x; v[5]=(f16)b.y; v[6]=(f16)b.z; v[7]=(f16)b.w;
    *(f16x8*)(dst + ((size_t)hgrp << 15) + (f << 9) + (l << 3)) = v;
  }
}

#define MFMA16(a,b,c) __builtin_amdgcn_mfma_f32_16x16x32_f16((a),(b),(c),0,0,0)

// ---- main: 256 blocks (128 hgrp x 2 bgrp) x 512 threads (8 col-group waves) ----
// LDS: Wih1 64KB | Whh1 64KB | h-stage 2KB | whh0f chunk dbuf 2x8KB = 146KB
__global__ void __launch_bounds__(512, 1) k_main(
    const float* __restrict__ Wih0, const float* __restrict__ Whh0,
    const float* __restrict__ bih0, const float* __restrict__ bhh0,
    const float* __restrict__ Wih1, const float* __restrict__ Whh1,
    const float* __restrict__ bih1, const float* __restrict__ bhh1,
    const float* __restrict__ fc_w, const float* __restrict__ fc_b,
    char* __restrict__ ws, float* __restrict__ out)
{
  extern __shared__ char smem_[];
  f16* lds = (f16*)smem_;          // halves: [0,32768) Wih1 frags | [32768,65536) Whh1 frags
  f16* stage  = lds + 65536;       // 1024 halves: [128 local cols][8 units]
  f16* wstage = lds + 66560;       // 8192 halves: 2 bufs x 4096 (whh0f chunk staging)

  const int tid  = threadIdx.x;
  const int blk  = blockIdx.x;
  const int hgrp = blk & 127;
  const int bgrp = blk >> 7;
  const int j0   = hgrp << 3;
  const int l    = tid & 63;
  const int w8   = tid >> 6;
  const int q    = l >> 4;
  const int c16  = l & 15;
  const int lcol = (w8 << 4) + c16;
  const int bcol = (bgrp << 7) + lcol;

  // ---- pack Wih1, Whh1 slices into LDS as MFMA A-frags (once) ----
  {
    const float* srcs[2] = {Wih1, Whh1};
#pragma unroll
    for (int m = 0; m < 2; ++m){
#pragma unroll
      for (int fi = 0; fi < 8; ++fi){
        const int f = (w8 << 3) + fi;
        const int c = f >> 1, T = f & 1;
        const int r = c16;
        const int uu = (T << 2) + (r >> 2);
        const int g = r & 3;
        const float* src = srcs[m] + (((size_t)((g << 10) + j0 + uu)) << 10) + (c << 5) + (q << 3);
        float4 a = *(const float4*)src;
        float4 b = *(const float4*)(src + 4);
        f16x8 v;
        v[0]=(f16)a.x; v[1]=(f16)a.y; v[2]=(f16)a.z; v[3]=(f16)a.w;
        v[4]=(f16)b.x; v[5]=(f16)b.y; v[6]=(f16)b.z; v[7]=(f16)b.w;
        *(f16x8*)(lds + m*32768 + (f << 9) + (l << 3)) = v;
      }
    }
  }
  __syncthreads();

  // ---- per-lane constants (units q and q+4) ----
  float bias0t[2][4], bias1t[2][4], wi0t[2][4];
#pragma unroll
  for (int t = 0; t < 2; ++t){
    const int uu = j0 + q + t*4;
#pragma unroll
    for (int g = 0; g < 4; ++g){
      int row = (g << 10) + uu;
      bias0t[t][g] = bih0[row] + bhh0[row];
      bias1t[t][g] = bih1[row] + bhh1[row];
      wi0t[t][g]   = Wih0[row];
    }
  }
  const float fcw0 = fc_w[j0 + q] * 1.25f;
  const float fcw1 = fc_w[j0 + q + 4] * 1.25f;
  const float fcb  = fc_b[0];

  const int base_h = (q << 11) + (bcol << 3);

  f16* H0 = (f16*)(ws + H0_OFF);
  f16* H1 = (f16*)(ws + H1_OFF);
  const f16* whh0f = (const f16*)(ws + WHH0F_OFF) + ((size_t)hgrp << 15);
  const float* seq = (const float*)(ws + SEQ_OFF);
  float* y_acc = (float*)(ws + YACC_OFF);
  unsigned* flagsH  = (unsigned*)(ws + FLAG_OFF) + bgrp*4352;
  unsigned* gflagsH = flagsH + 128*32;

  // ---- whh0f resident in registers (8 chunks x 16B/thread) ----
  u32x4 wreg[8];
#pragma unroll
  for (int ch = 0; ch < 8; ++ch)
    wreg[ch] = *(const u32x4*)(whh0f + ((size_t)ch << 12) + (tid << 3));

  // ---- 4-slot rolling prefetch of phase-A h groups (slots 0,1 cross barriers) ----
  f16x8 BhP[4][4];
  {
    const f16* a00 = H0 + base_h;      // src buf 0 (zeroed)
#pragma unroll
    for (int i = 0; i < 4; ++i){
      BhP[0][i] = *(const f16x8*)(a00 + i*8192);
      BhP[1][i] = *(const f16x8*)(a00 + (4+i)*8192);
    }
  }

  float c0[2] = {0,0}, c1[2] = {0,0};
  float yprev = 0.f;
  unsigned ep = 0;

#pragma unroll 1
  for (int s = 0; s < 107; ++s){
    const int src = s & 1, dst = src ^ 1;

    if (s >= 84){
      const int tp = s - 84;
      yprev = fcb + __uint_as_float(ld_dword_sc(y_acc + (tp << 8) + bcol));
      if (hgrp == 0 && q == 0) out[bcol*24 + tp] = yprev;
    }
    // resolve x_t early (overlaps phase A)
    float xb = (s < 84) ? seq[(s << 8) + bcol] : yprev;

    // ========= phase A: gates0 = Whh0*h0 (reg weights via LDS chunks, 4-deep h pipe) =========
    float h0n[2];
    {
      const f16* a0 = H0 + src*262144 + base_h;
      f32x4 acc0 = (f32x4){0,0,0,0}, acc1 = (f32x4){0,0,0,0};
      *(u32x4*)(wstage + (tid << 3)) = wreg[0];   // publish chunk 0 -> buf 0
#define LDH(B, C0) { _Pragma("unroll") for (int i = 0; i < 4; ++i){ \
      BhP[B][i] = *(const f16x8*)(a0 + ((C0)+i)*8192); } }
#define MMW(B, CH) { const f16* wsb = wstage + (((CH)&1) << 12) + (l << 3); \
      _Pragma("unroll") for (int i = 0; i < 4; ++i){ \
      f16x8 wf0 = *(const f16x8*)(wsb + ((2*i  ) << 9)); \
      f16x8 wf1 = *(const f16x8*)(wsb + ((2*i+1) << 9)); \
      acc0 = MFMA16(wf0, BhP[B][i], acc0); \
      acc1 = MFMA16(wf1, BhP[B][i], acc1); } }
      LDH(2, 8) LDH(3, 12)      // slots 0,1 pre-filled by tail prefetch; fill 2,3
      __syncthreads();
#pragma unroll
      for (int ch = 0; ch < 8; ++ch){
        if (ch < 7) *(u32x4*)(wstage + (((ch+1)&1) << 12) + (tid << 3)) = wreg[ch+1];
        MMW(ch&3, ch)
        if (ch < 4) LDH(ch&3, (ch+4)*4)
        if (ch < 7) __syncthreads();
      }
#undef LDH
#undef MMW
      f32x4 at[2] = {acc0, acc1};
#pragma unroll
      for (int t = 0; t < 2; ++t){
        float pi = at[t][0] + bias0t[t][0] + wi0t[t][0]*xb;
        float pf = at[t][1] + bias0t[t][1] + wi0t[t][1]*xb;
        float pg = at[t][2] + bias0t[t][2] + wi0t[t][2]*xb;
        float po = at[t][3] + bias0t[t][3] + wi0t[t][3]*xb;
        c0[t]  = sigf(pf)*c0[t] + sigf(pi)*thf(pg);
        h0n[t] = sigf(po)*thf(c0[t]);
        stage[(lcol << 3) + q + t*4] = (f16)h0n[t];
      }
    }
    __syncthreads();
    if (tid < 128){
      u32x4 v = ((const u32x4*)stage)[tid];
      st_dwordx4_sc((char*)(H0 + dst*262144 + (hgrp << 11) + (bgrp << 10)) + tid*16, v);
    }
    ++ep; gbar(flagsH, gflagsH, ep, tid, hgrp, true);   // mid barrier WITH inv

    // ========= phase B: gates1 = Wih1*h0new + Whh1*h1 (LDS weights, 4-deep pipe) =========
    float h1n[2];
    {
      const f16* b0 = H0 + dst*262144 + base_h;
      const f16* b1 = H1 + src*262144 + base_h;
      f16x8 X0[4][4], X1[4][4];
      f32x4 acc0 = (f32x4){0,0,0,0}, acc1 = (f32x4){0,0,0,0};
#define LDB(B, CB) { _Pragma("unroll") for (int i = 0; i < 4; ++i){ const int c = (CB)+i; \
      X0[B][i] = *(const f16x8*)(b0 + c*8192); \
      X1[B][i] = *(const f16x8*)(b1 + c*8192); } }
#define MMB(B, CB) { _Pragma("unroll") for (int i = 0; i < 4; ++i){ const int c = (CB)+i; \
      f16x8 wa0 = *(const f16x8*)(lds + ((2*c  ) << 9) + (l << 3)); \
      f16x8 wa1 = *(const f16x8*)(lds + ((2*c+1) << 9) + (l << 3)); \
      f16x8 wb0 = *(const f16x8*)(lds + 32768 + ((2*c  ) << 9) + (l << 3)); \
      f16x8 wb1 = *(const f16x8*)(lds + 32768 + ((2*c+1) << 9) + (l << 3)); \
      acc0 = MFMA16(wa0, X0[B][i], acc0); \
      acc0 = MFMA16(wb0, X1[B][i], acc0); \
      acc1 = MFMA16(wa1, X0[B][i], acc1); \
      acc1 = MFMA16(wb1, X1[B][i], acc1); } }
      LDB(0, 0) LDB(1, 4) LDB(2, 8) LDB(3, 12)   // 32 loads in flight
#pragma unroll
      for (int cb = 0; cb < 8; ++cb){
        MMB(cb&3, cb*4)
        if (cb < 4) LDB(cb&3, (cb+4)*4)
      }
#undef LDB
#undef MMB
      f32x4 at[2] = {acc0, acc1};
#pragma unroll
      for (int t = 0; t < 2; ++t){
        float pi = at[t][0] + bias1t[t][0];
        float pf = at[t][1] + bias1t[t][1];
        float pg = at[t][2] + bias1t[t][2];
        float po = at[t][3] + bias1t[t][3];
        c1[t]  = sigf(pf)*c1[t] + sigf(pi)*thf(pg);
        h1n[t] = sigf(po)*thf(c1[t]);
        stage[(lcol << 3) + q + t*4] = (f16)h1n[t];
      }
    }
    __syncthreads();
    if (tid < 128){
      u32x4 v = ((const u32x4*)stage)[tid];
      st_dwordx4_sc((char*)(H1 + dst*262144 + (hgrp << 11) + (bgrp << 10)) + tid*16, v);
    }
    __syncthreads();   // protect stage from next phase-A overwrite

    // ---- tail prefetch: next step's phase-A h groups 0,1 (final + L2-fresh) ----
    {
      const f16* a0n = H0 + dst*262144 + base_h;
#pragma unroll
      for (int i = 0; i < 4; ++i){
        BhP[0][i] = *(const f16x8*)(a0n + i*8192);
        BhP[1][i] = *(const f16x8*)(a0n + (4+i)*8192);
      }
    }

    // ---- fc partials with exact JAX dropout (tau = s-83) ----
    if (s >= 83){
      const int tau = s - 83;
      uint2 fk = tf2x32(0u, 42u, 0u, (unsigned)tau);
      unsigned n0 = ((unsigned)bcol << 10) + (unsigned)(j0 + q);
      unsigned n1 = n0 + 4u;
      float v = (drop_keep(fk, n0) ? h1n[0]*fcw0 : 0.f)
              + (drop_keep(fk, n1) ? h1n[1]*fcw1 : 0.f);
      v += __shfl_xor(v, 16, 64);
      v += __shfl_xor(v, 32, 64);
      if (q == 0) atomicAdd(y_acc + (tau << 8) + bcol, v);
      ++ep; gbar(flagsH, gflagsH, ep, tid, hgrp, false);  // end barrier, NO inv
    }
  }

  // tail: y_23 (LLC-coherent read)
  if (hgrp == 0 && q == 0)
    out[bcol*24 + 23] = fcb + __uint_as_float(ld_dword_sc(y_acc + (23 << 8) + bcol));
}

extern "C" void kernel_launch(void* const* d_in, const int* in_sizes, int n_in,
                              void* d_out, int out_size, void* d_ws, size_t ws_size,
                              hipStream_t stream)
{
  const float* x    = (const float*)d_in[0];
  const float* cw   = (const float*)d_in[1];
  const float* cb   = (const float*)d_in[2];
  const float* Wih0 = (const float*)d_in[3];
  const float* Whh0 = (const float*)d_in[4];
  const float* bih0 = (const float*)d_in[5];
  const float* bhh0 = (const float*)d_in[6];
  const float* Wih1 = (const float*)d_in[7];
  const float* Whh1 = (const float*)d_in[8];
  const float* bih1 = (const float*)d_in[9];
  const float* bhh1 = (const float*)d_in[10];
  const float* fc_w = (const float*)d_in[11];
  const float* fc_b = (const float*)d_in[12];
  float* out = (float*)d_out;
  char*  ws  = (char*)d_ws;

  hipLaunchKernelGGL(k_init, dim3(1040), dim3(256), 0, stream,
                     (uint4*)(ws + H0_OFF), (uint4*)(ws + YACC_OFF), (uint4*)(ws + FLAG_OFF));
  hipLaunchKernelGGL(k_seq,  dim3(84), dim3(256), 0, stream, x, cw, cb, (float*)(ws + SEQ_OFF));
  hipLaunchKernelGGL(k_wpack, dim3(128), dim3(512), 0, stream, Whh0, (f16*)(ws + WHH0F_OFF));
  hipLaunchKernelGGL(k_main, dim3(256), dim3(512), 149504, stream,
                     Wih0, Whh0, bih0, bhh0, Wih1, Whh1, bih1, bhh1,
                     fc_w, fc_b, ws, out);
}

// Round 19
// 2864.717 us; speedup vs baseline: 1.9826x; 1.1377x over previous
//
#include <hip/hip_runtime.h>
#include <stdint.h>

typedef _Float16 f16;
typedef f16  f16x8 __attribute__((ext_vector_type(8)));
typedef float f32x4 __attribute__((ext_vector_type(4)));
typedef unsigned u32x4 __attribute__((ext_vector_type(4)));

// ---------------- ws layout (byte offsets) ----------------
// H0/H1: 2 bufs x [k/8][b][8] f16 (fp16-only h, 512KB per buf)
// WHH0F: fp16 MFMA A-frags of Whh0, [hgrp128][frag64][lane64][8] = 8 MB
// SEQ [84][256] f32 | YACC [24][256] f32 | FLAG 2 halves x (128+8) x 128B
#define H0_OFF    0u
#define H1_OFF    2097152u
#define WHH0F_OFF 4194304u
#define SEQ_OFF   12582912u
#define YACC_OFF  12668928u
#define FLAG_OFF  12693504u

__device__ __forceinline__ unsigned rotl32(unsigned x, int d){ return (x<<d)|(x>>(32-d)); }

// Threefry-2x32, 20 rounds, exactly JAX's key schedule. (bit-exact, proven R1-R18)
__device__ __forceinline__ uint2 tf2x32(unsigned k0, unsigned k1, unsigned x0, unsigned x1){
  unsigned kx = k0 ^ k1 ^ 0x1BD11BDAu;
  x0 += k0; x1 += k1;
#define TFR(r) { x0 += x1; x1 = rotl32(x1,(r)); x1 ^= x0; }
  TFR(13) TFR(15) TFR(26) TFR(6)  x0 += k1; x1 += kx + 1u;
  TFR(17) TFR(29) TFR(16) TFR(24) x0 += kx; x1 += k0 + 2u;
  TFR(13) TFR(15) TFR(26) TFR(6)  x0 += k0; x1 += k1 + 3u;
  TFR(17) TFR(29) TFR(16) TFR(24) x0 += k1; x1 += kx + 4u;
  TFR(13) TFR(15) TFR(26) TFR(6)  x0 += kx; x1 += k0 + 5u;
#undef TFR
  return make_uint2(x0, x1);
}

__device__ __forceinline__ bool drop_keep(uint2 fk, unsigned n){
  uint2 o = tf2x32(fk.x, fk.y, 0u, n);
  unsigned bits = o.x ^ o.y;
  float u = __uint_as_float((bits >> 9) | 0x3f800000u) - 1.0f;
  return u < 0.8f;
}

__device__ __forceinline__ float sigf(float x){ return 1.0f/(1.0f + __expf(-x)); }
__device__ __forceinline__ float thf(float x){ return 1.0f - 2.0f/(__expf(2.0f*x) + 1.0f); }

// ---- LLC-coherent accessors (proven R4-R18) ----
__device__ __forceinline__ void st_dword_sc(void* p, unsigned v){
  asm volatile("global_store_dword %0, %1, off sc0 sc1" :: "v"(p), "v"(v) : "memory");
}
__device__ __forceinline__ void st_dwordx4_sc(void* p, u32x4 v){
  asm volatile("global_store_dwordx4 %0, %1, off sc0 sc1" :: "v"(p), "v"(v) : "memory");
}
__device__ __forceinline__ unsigned ld_dword_sc(const void* p){
  unsigned r;
  asm volatile("global_load_dword %0, %1, off sc0 sc1\n\ts_waitcnt vmcnt(0)"
               : "=v"(r) : "v"(p) : "memory");
  return r;
}

// Per-half 2-level tree barrier: 128 blocks, 8 leaders x 16 flags; inv optional.
__device__ __forceinline__ void gbar(unsigned* flagsH, unsigned* gflagsH, unsigned e,
                                     int tid, int lblk, bool inv){
  asm volatile("s_waitcnt vmcnt(0)" ::: "memory");
  __syncthreads();
  if (tid == 0) st_dword_sc(flagsH + lblk*32, e);
  if (lblk < 8){
    if (tid < 16){
      unsigned* f = flagsH + (lblk*16 + tid)*32;
      while (ld_dword_sc(f) < e) __builtin_amdgcn_s_sleep(1);
    }
    __syncthreads();
    if (tid == 0) st_dword_sc(gflagsH + lblk*32, e);
  }
  if (tid < 8){
    unsigned* f = gflagsH + tid*32;
    while (ld_dword_sc(f) < e) __builtin_amdgcn_s_sleep(1);
  }
  __syncthreads();
  if (inv) __builtin_amdgcn_fence(__ATOMIC_ACQUIRE, "agent");
  __builtin_amdgcn_sched_barrier(0);
}

// ---- prep: zero h buffers + y_acc + flags ----
__global__ void k_init(uint4* __restrict__ hz, uint4* __restrict__ yz, uint4* __restrict__ fz){
  unsigned i = blockIdx.x*256u + threadIdx.x;
  if (i < 262144u){ hz[i] = uint4{0,0,0,0}; }
  else if (i < 263680u){ yz[i - 262144u] = uint4{0,0,0,0}; }
  else if (i < 265856u){ fz[i - 263680u] = uint4{0,0,0,0}; }
}

// ---- prep: conv1d(pad1,k3) + relu + maxpool2 -> seq[84][256] ----
__global__ void k_seq(const float* __restrict__ x, const float* __restrict__ cw,
                      const float* __restrict__ cb, float* __restrict__ seq){
  const int q = blockIdx.x;
  const int b = threadIdx.x;
  float best = -1e30f;
#pragma unroll
  for (int ssub = 0; ssub < 2; ++ssub){
    int p = 2*q + ssub;
    float acc = cb[0];
#pragma unroll
    for (int k = 0; k < 3; ++k){
      int t = p - 1 + k;
      if (t >= 0 && t < 168){
        const float* xp = x + ((size_t)b*192 + t)*8;
#pragma unroll
        for (int i = 0; i < 8; ++i) acc = fmaf(xp[i], cw[i*3 + k], acc);
      }
    }
    acc  = fmaxf(acc, 0.0f);
    best = fmaxf(best, acc);
  }
  seq[(q<<8) + b] = best;
}

// ---- prep: pack Whh0 (fp32 [4096][1024]) into fp16 MFMA A-frags per hgrp ----
__global__ void __launch_bounds__(512) k_wpack(const float* __restrict__ W, f16* __restrict__ dst){
  const int hgrp = blockIdx.x;       // 0..127
  const int tid = threadIdx.x;
  const int l   = tid & 63;
  const int w   = tid >> 6;          // 0..7
  const int j0  = hgrp << 3;
#pragma unroll
  for (int fi = 0; fi < 8; ++fi){
    const int f = (w << 3) + fi;     // 0..63
    const int c = f >> 1, T = f & 1;
    const int r = l & 15;
    const int u = (T << 2) + (r >> 2);
    const int g = r & 3;
    const float* src = W + (((size_t)((g << 10) + j0 + u)) << 10) + (c << 5) + ((l >> 4) << 3);
    float4 a = *(const float4*)src;
    float4 b = *(const float4*)(src + 4);
    f16x8 v;
    v[0]=(f16)a.x; v[1]=(f16)a.y; v[2]=(f16)a.z; v[3]=(f16)a.w;
    v[4]=(f16)b.x; v[5]=(f16)b.y; v[6]=(f16)b.z; v[7]=(f16)b.w;
    *(f16x8*)(dst + ((size_t)hgrp << 15) + (f << 9) + (l << 3)) = v;
  }
}

#define MFMA16(a,b,c) __builtin_amdgcn_mfma_f32_16x16x32_f16((a),(b),(c),0,0,0)

// ---- main: 256 blocks (128 hgrp x 2 bgrp) x 512 threads ----
// Merged-region schedule: midbar(s) -> [B(s) || A(s+1), SHARED h0new loads] ->
// B-epi -> (fc+endbar | sync) -> A-epi(xb) -> midbar(s+1).
// LDS: Wih1 64KB | Whh1 64KB | h-stage 2KB | whh0f chunk dbuf 2x8KB = 146KB
__global__ void __launch_bounds__(512, 1) k_main(
    const float* __restrict__ Wih0, const float* __restrict__ Whh0,
    const float* __restrict__ bih0, const float* __restrict__ bhh0,
    const float* __restrict__ Wih1, const float* __restrict__ Whh1,
    const float* __restrict__ bih1, const float* __restrict__ bhh1,
    const float* __restrict__ fc_w, const float* __restrict__ fc_b,
    char* __restrict__ ws, float* __restrict__ out)
{
  extern __shared__ char smem_[];
  f16* lds = (f16*)smem_;          // halves: [0,32768) Wih1 frags | [32768,65536) Whh1 frags
  f16* stage  = lds + 65536;       // 1024 halves: [128 local cols][8 units]
  f16* wstage = lds + 66560;       // 8192 halves: 2 bufs x 4096 (whh0f chunk staging)

  const int tid  = threadIdx.x;
  const int blk  = blockIdx.x;
  const int hgrp = blk & 127;
  const int bgrp = blk >> 7;
  const int j0   = hgrp << 3;
  const int l    = tid & 63;
  const int w8   = tid >> 6;
  const int q    = l >> 4;
  const int c16  = l & 15;
  const int lcol = (w8 << 4) + c16;
  const int bcol = (bgrp << 7) + lcol;

  // ---- pack Wih1, Whh1 slices into LDS as MFMA A-frags (once) ----
  {
    const float* srcs[2] = {Wih1, Whh1};
#pragma unroll
    for (int m = 0; m < 2; ++m){
#pragma unroll
      for (int fi = 0; fi < 8; ++fi){
        const int f = (w8 << 3) + fi;
        const int c = f >> 1, T = f & 1;
        const int r = c16;
        const int uu = (T << 2) + (r >> 2);
        const int g = r & 3;
        const float* src = srcs[m] + (((size_t)((g << 10) + j0 + uu)) << 10) + (c << 5) + (q << 3);
        float4 a = *(const float4*)src;
        float4 b = *(const float4*)(src + 4);
        f16x8 v;
        v[0]=(f16)a.x; v[1]=(f16)a.y; v[2]=(f16)a.z; v[3]=(f16)a.w;
        v[4]=(f16)b.x; v[5]=(f16)b.y; v[6]=(f16)b.z; v[7]=(f16)b.w;
        *(f16x8*)(lds + m*32768 + (f << 9) + (l << 3)) = v;
      }
    }
  }
  __syncthreads();

  // ---- per-lane constants (units q and q+4) ----
  float bias0t[2][4], bias1t[2][4], wi0t[2][4];
#pragma unroll
  for (int t = 0; t < 2; ++t){
    const int uu = j0 + q + t*4;
#pragma unroll
    for (int g = 0; g < 4; ++g){
      int row = (g << 10) + uu;
      bias0t[t][g] = bih0[row] + bhh0[row];
      bias1t[t][g] = bih1[row] + bhh1[row];
      wi0t[t][g]   = Wih0[row];
    }
  }
  const float fcw0 = fc_w[j0 + q] * 1.25f;
  const float fcw1 = fc_w[j0 + q + 4] * 1.25f;
  const float fcb  = fc_b[0];

  const int base_h = (q << 11) + (bcol << 3);

  f16* H0 = (f16*)(ws + H0_OFF);
  f16* H1 = (f16*)(ws + H1_OFF);
  const f16* whh0f = (const f16*)(ws + WHH0F_OFF) + ((size_t)hgrp << 15);
  const float* seq = (const float*)(ws + SEQ_OFF);
  float* y_acc = (float*)(ws + YACC_OFF);
  unsigned* flagsH  = (unsigned*)(ws + FLAG_OFF) + bgrp*4352;
  unsigned* gflagsH = flagsH + 128*32;

  // ---- whh0f resident in registers (8 chunks x 16B/thread) ----
  u32x4 wreg[8];
#pragma unroll
  for (int ch = 0; ch < 8; ++ch)
    wreg[ch] = *(const u32x4*)(whh0f + ((size_t)ch << 12) + (tid << 3));

  float c0[2] = {0,0}, c1[2] = {0,0};
  unsigned ep = 0;

  // ---- prologue: A(0) with h0=0 -> acc==0, gates = bias + wi0*x; publish h0 buf1 ----
  {
    float xb = seq[bcol];
#pragma unroll
    for (int t = 0; t < 2; ++t){
      float pi = bias0t[t][0] + wi0t[t][0]*xb;
      float pf = bias0t[t][1] + wi0t[t][1]*xb;
      float pg = bias0t[t][2] + wi0t[t][2]*xb;
      float po = bias0t[t][3] + wi0t[t][3]*xb;
      c0[t] = sigf(pi)*thf(pg);              // f*c0(=0) dropped
      float h0n = sigf(po)*thf(c0[t]);
      stage[(lcol << 3) + q + t*4] = (f16)h0n;
    }
  }
  __syncthreads();
  if (tid < 128){
    u32x4 v = ((const u32x4*)stage)[tid];
    st_dwordx4_sc((char*)(H0 + 262144 + (hgrp << 11) + (bgrp << 10)) + tid*16, v);
  }
  ++ep; gbar(flagsH, gflagsH, ep, tid, hgrp, true);   // midbar(0)

#pragma unroll 1
  for (int s = 0; s < 107; ++s){
    const int p = s & 1;
    const bool doA = (s < 106);
    const f16* hb0 = H0 + (p^1)*262144 + base_h;   // h0new(s): shared B + A(s+1) operand
    const f16* hb1 = H1 + p*262144 + base_h;       // h1(s-1)

    // ========= merged region: B(s) [128 MFMA] || A(s+1) [64 MFMA], shared X0 =========
    f16x8 X0[2][4], X1[2][4];
    f32x4 accB0 = (f32x4){0,0,0,0}, accB1 = (f32x4){0,0,0,0};
    f32x4 accA0 = (f32x4){0,0,0,0}, accA1 = (f32x4){0,0,0,0};
#define LDX(B, CB) { _Pragma("unroll") for (int i = 0; i < 4; ++i){ const int c = (CB)+i; \
      X0[B][i] = *(const f16x8*)(hb0 + c*8192); \
      X1[B][i] = *(const f16x8*)(hb1 + c*8192); } }
#define MMW(B, CH) { const f16* wsb = wstage + (((CH)&1) << 12) + (l << 3); \
      _Pragma("unroll") for (int i = 0; i < 4; ++i){ \
      f16x8 wf0 = *(const f16x8*)(wsb + ((2*i  ) << 9)); \
      f16x8 wf1 = *(const f16x8*)(wsb + ((2*i+1) << 9)); \
      accA0 = MFMA16(wf0, X0[B][i], accA0); \
      accA1 = MFMA16(wf1, X0[B][i], accA1); } }
#define MMB(B, CB) { _Pragma("unroll") for (int i = 0; i < 4; ++i){ const int c = (CB)+i; \
      f16x8 wa0 = *(const f16x8*)(lds + ((2*c  ) << 9) + (l << 3)); \
      f16x8 wa1 = *(const f16x8*)(lds + ((2*c+1) << 9) + (l << 3)); \
      f16x8 wb0 = *(const f16x8*)(lds + 32768 + ((2*c  ) << 9) + (l << 3)); \
      f16x8 wb1 = *(const f16x8*)(lds + 32768 + ((2*c+1) << 9) + (l << 3)); \
      accB0 = MFMA16(wa0, X0[B][i], accB0); \
      accB0 = MFMA16(wb0, X1[B][i], accB0); \
      accB1 = MFMA16(wa1, X0[B][i], accB1); \
      accB1 = MFMA16(wb1, X1[B][i], accB1); } }
    LDX(0, 0) LDX(1, 4)
    *(u32x4*)(wstage + (tid << 3)) = wreg[0];
    __syncthreads();
#pragma unroll
    for (int ch = 0; ch < 8; ++ch){
      if (ch < 7) *(u32x4*)(wstage + (((ch+1)&1) << 12) + (tid << 3)) = wreg[ch+1];
      if (doA) MMW(ch&1, ch)
      MMB(ch&1, ch*4)
      if (ch < 6) LDX(ch&1, (ch+2)*4)
      if (ch < 7) __syncthreads();
    }
#undef LDX
#undef MMW
#undef MMB

    // ---- B epilogue: h1n, publish h1[p^1] ----
    float h1n[2];
    {
      f32x4 at[2] = {accB0, accB1};
#pragma unroll
      for (int t = 0; t < 2; ++t){
        float pi = at[t][0] + bias1t[t][0];
        float pf = at[t][1] + bias1t[t][1];
        float pg = at[t][2] + bias1t[t][2];
        float po = at[t][3] + bias1t[t][3];
        c1[t]  = sigf(pf)*c1[t] + sigf(pi)*thf(pg);
        h1n[t] = sigf(po)*thf(c1[t]);
        stage[(lcol << 3) + q + t*4] = (f16)h1n[t];
      }
    }
    __syncthreads();
    if (tid < 128){
      u32x4 v = ((const u32x4*)stage)[tid];
      st_dwordx4_sc((char*)(H1 + (p^1)*262144 + (hgrp << 11) + (bgrp << 10)) + tid*16, v);
    }

    // ---- fc + endbar (decoder), else local sync to protect stage ----
    if (s >= 83){
      const int tau = s - 83;
      uint2 fk = tf2x32(0u, 42u, 0u, (unsigned)tau);
      unsigned n0 = ((unsigned)bcol << 10) + (unsigned)(j0 + q);
      unsigned n1 = n0 + 4u;
      float v = (drop_keep(fk, n0) ? h1n[0]*fcw0 : 0.f)
              + (drop_keep(fk, n1) ? h1n[1]*fcw1 : 0.f);
      v += __shfl_xor(v, 16, 64);
      v += __shfl_xor(v, 32, 64);
      if (q == 0) atomicAdd(y_acc + (tau << 8) + bcol, v);
      ++ep; gbar(flagsH, gflagsH, ep, tid, hgrp, false);   // endbar(s), NO inv
    } else {
      __syncthreads();
    }

    // ---- A(s+1) epilogue: xb, gates from accA, publish h0[p]; midbar(s+1) ----
    if (doA){
      const int s1 = s + 1;
      float xb;
      if (s1 < 84){
        xb = seq[(s1 << 8) + bcol];
      } else {
        const int tp = s1 - 84;
        float yp = fcb + __uint_as_float(ld_dword_sc(y_acc + (tp << 8) + bcol));
        if (hgrp == 0 && q == 0) out[bcol*24 + tp] = yp;
        xb = yp;
      }
      f32x4 at[2] = {accA0, accA1};
#pragma unroll
      for (int t = 0; t < 2; ++t){
        float pi = at[t][0] + bias0t[t][0] + wi0t[t][0]*xb;
        float pf = at[t][1] + bias0t[t][1] + wi0t[t][1]*xb;
        float pg = at[t][2] + bias0t[t][2] + wi0t[t][2]*xb;
        float po = at[t][3] + bias0t[t][3] + wi0t[t][3]*xb;
        c0[t]  = sigf(pf)*c0[t] + sigf(pi)*thf(pg);
        float h0n = sigf(po)*thf(c0[t]);
        stage[(lcol << 3) + q + t*4] = (f16)h0n;
      }
      __syncthreads();
      if (tid < 128){
        u32x4 v = ((const u32x4*)stage)[tid];
        st_dwordx4_sc((char*)(H0 + p*262144 + (hgrp << 11) + (bgrp << 10)) + tid*16, v);
      }
      ++ep; gbar(flagsH, gflagsH, ep, tid, hgrp, true);    // midbar(s+1) WITH inv
    }
  }

  // tail: y_23 (after endbar(106); LLC-coherent read)
  if (hgrp == 0 && q == 0)
    out[bcol*24 + 23] = fcb + __uint_as_float(ld_dword_sc(y_acc + (23 << 8) + bcol));
}

extern "C" void kernel_launch(void* const* d_in, const int* in_sizes, int n_in,
                              void* d_out, int out_size, void* d_ws, size_t ws_size,
                              hipStream_t stream)
{
  const float* x    = (const float*)d_in[0];
  const float* cw   = (const float*)d_in[1];
  const float* cb   = (const float*)d_in[2];
  const float* Wih0 = (const float*)d_in[3];
  const float* Whh0 = (const float*)d_in[4];
  const float* bih0 = (const float*)d_in[5];
  const float* bhh0 = (const float*)d_in[6];
  const float* Wih1 = (const float*)d_in[7];
  const float* Whh1 = (const float*)d_in[8];
  const float* bih1 = (const float*)d_in[9];
  const float* bhh1 = (const float*)d_in[10];
  const float* fc_w = (const float*)d_in[11];
  const float* fc_b = (const float*)d_in[12];
  float* out = (float*)d_out;
  char*  ws  = (char*)d_ws;

  hipLaunchKernelGGL(k_init, dim3(1040), dim3(256), 0, stream,
                     (uint4*)(ws + H0_OFF), (uint4*)(ws + YACC_OFF), (uint4*)(ws + FLAG_OFF));
  hipLaunchKernelGGL(k_seq,  dim3(84), dim3(256), 0, stream, x, cw, cb, (float*)(ws + SEQ_OFF));
  hipLaunchKernelGGL(k_wpack, dim3(128), dim3(512), 0, stream, Whh0, (f16*)(ws + WHH0F_OFF));
  hipLaunchKernelGGL(k_main, dim3(256), dim3(512), 149504, stream,
                     Wih0, Whh0, bih0, bhh0, Wih1, Whh1, bih1, bhh1,
                     fc_w, fc_b, ws, out);
}

// Round 20
// 2801.970 us; speedup vs baseline: 2.0270x; 1.0224x over previous
//
#include <hip/hip_runtime.h>
#include <stdint.h>

typedef _Float16 f16;
typedef f16  f16x8 __attribute__((ext_vector_type(8)));
typedef float f32x4 __attribute__((ext_vector_type(4)));
typedef unsigned u32x4 __attribute__((ext_vector_type(4)));

// ---------------- ws layout (byte offsets) ----------------
// H0/H1: 2 bufs x [k/8][b][8] f16 (fp16-only h, 512KB per buf)
// WHH0F: fp16 MFMA A-frags of Whh0, [hgrp128][frag64][lane64][8] = 8 MB
// SEQ [84][256] f32 | YACC [24][256] f32 | FLAG 2 halves x 128 x 128B
#define H0_OFF    0u
#define H1_OFF    2097152u
#define WHH0F_OFF 4194304u
#define SEQ_OFF   12582912u
#define YACC_OFF  12668928u
#define FLAG_OFF  12693504u

__device__ __forceinline__ unsigned rotl32(unsigned x, int d){ return (x<<d)|(x>>(32-d)); }

// Threefry-2x32, 20 rounds, exactly JAX's key schedule. (bit-exact, proven R1-R19)
__device__ __forceinline__ uint2 tf2x32(unsigned k0, unsigned k1, unsigned x0, unsigned x1){
  unsigned kx = k0 ^ k1 ^ 0x1BD11BDAu;
  x0 += k0; x1 += k1;
#define TFR(r) { x0 += x1; x1 = rotl32(x1,(r)); x1 ^= x0; }
  TFR(13) TFR(15) TFR(26) TFR(6)  x0 += k1; x1 += kx + 1u;
  TFR(17) TFR(29) TFR(16) TFR(24) x0 += kx; x1 += k0 + 2u;
  TFR(13) TFR(15) TFR(26) TFR(6)  x0 += k0; x1 += k1 + 3u;
  TFR(17) TFR(29) TFR(16) TFR(24) x0 += k1; x1 += kx + 4u;
  TFR(13) TFR(15) TFR(26) TFR(6)  x0 += kx; x1 += k0 + 5u;
#undef TFR
  return make_uint2(x0, x1);
}

__device__ __forceinline__ bool drop_keep(uint2 fk, unsigned n){
  uint2 o = tf2x32(fk.x, fk.y, 0u, n);
  unsigned bits = o.x ^ o.y;
  float u = __uint_as_float((bits >> 9) | 0x3f800000u) - 1.0f;
  return u < 0.8f;
}

__device__ __forceinline__ float sigf(float x){ return 1.0f/(1.0f + __expf(-x)); }
__device__ __forceinline__ float thf(float x){ return 1.0f - 2.0f/(__expf(2.0f*x) + 1.0f); }

// ---- LLC-coherent accessors (proven R4-R19) ----
__device__ __forceinline__ void st_dword_sc(void* p, unsigned v){
  asm volatile("global_store_dword %0, %1, off sc0 sc1" :: "v"(p), "v"(v) : "memory");
}
__device__ __forceinline__ void st_dwordx4_sc(void* p, u32x4 v){
  asm volatile("global_store_dwordx4 %0, %1, off sc0 sc1" :: "v"(p), "v"(v) : "memory");
}
__device__ __forceinline__ unsigned ld_dword_sc(const void* p){
  unsigned r;
  asm volatile("global_load_dword %0, %1, off sc0 sc1\n\ts_waitcnt vmcnt(0)"
               : "=v"(r) : "v"(p) : "memory");
  return r;
}

// FLAT per-half barrier: 128 blocks; thread t<128 polls flag t. One LLC
// round-trip after last arrival; no leader aggregation (tree's 2nd RT + leader
// imbalance removed). inv optional per call site.
__device__ __forceinline__ void gbar(unsigned* flagsH, unsigned e,
                                     int tid, int lblk, bool inv){
  asm volatile("s_waitcnt vmcnt(0)" ::: "memory");
  __syncthreads();
  if (tid == 0) st_dword_sc(flagsH + lblk*32, e);
  if (tid < 128){
    unsigned* f = flagsH + tid*32;
    while (ld_dword_sc(f) < e) __builtin_amdgcn_s_sleep(1);
  }
  __syncthreads();
  if (inv) __builtin_amdgcn_fence(__ATOMIC_ACQUIRE, "agent");
  __builtin_amdgcn_sched_barrier(0);
}

// ---- prep: zero h buffers + y_acc + flags ----
__global__ void k_init(uint4* __restrict__ hz, uint4* __restrict__ yz, uint4* __restrict__ fz){
  unsigned i = blockIdx.x*256u + threadIdx.x;
  if (i < 262144u){ hz[i] = uint4{0,0,0,0}; }
  else if (i < 263680u){ yz[i - 262144u] = uint4{0,0,0,0}; }
  else if (i < 265728u){ fz[i - 263680u] = uint4{0,0,0,0}; }
}

// ---- prep: conv1d(pad1,k3) + relu + maxpool2 -> seq[84][256] ----
__global__ void k_seq(const float* __restrict__ x, const float* __restrict__ cw,
                      const float* __restrict__ cb, float* __restrict__ seq){
  const int q = blockIdx.x;
  const int b = threadIdx.x;
  float best = -1e30f;
#pragma unroll
  for (int ssub = 0; ssub < 2; ++ssub){
    int p = 2*q + ssub;
    float acc = cb[0];
#pragma unroll
    for (int k = 0; k < 3; ++k){
      int t = p - 1 + k;
      if (t >= 0 && t < 168){
        const float* xp = x + ((size_t)b*192 + t)*8;
#pragma unroll
        for (int i = 0; i < 8; ++i) acc = fmaf(xp[i], cw[i*3 + k], acc);
      }
    }
    acc  = fmaxf(acc, 0.0f);
    best = fmaxf(best, acc);
  }
  seq[(q<<8) + b] = best;
}

// ---- prep: pack Whh0 (fp32 [4096][1024]) into fp16 MFMA A-frags per hgrp ----
__global__ void __launch_bounds__(512) k_wpack(const float* __restrict__ W, f16* __restrict__ dst){
  const int hgrp = blockIdx.x;       // 0..127
  const int tid = threadIdx.x;
  const int l   = tid & 63;
  const int w   = tid >> 6;          // 0..7
  const int j0  = hgrp << 3;
#pragma unroll
  for (int fi = 0; fi < 8; ++fi){
    const int f = (w << 3) + fi;     // 0..63
    const int c = f >> 1, T = f & 1;
    const int r = l & 15;
    const int u = (T << 2) + (r >> 2);
    const int g = r & 3;
    const float* src = W + (((size_t)((g << 10) + j0 + u)) << 10) + (c << 5) + ((l >> 4) << 3);
    float4 a = *(const float4*)src;
    float4 b = *(const float4*)(src + 4);
    f16x8 v;
    v[0]=(f16)a.x; v[1]=(f16)a.y; v[2]=(f16)a.z; v[3]=(f16)a.w;
    v[4]=(f16)b.x; v[5]=(f16)b.y; v[6]=(f16)b.z; v[7]=(f16)b.w;
    *(f16x8*)(dst + ((size_t)hgrp << 15) + (f << 9) + (l << 3)) = v;
  }
}

#define MFMA16(a,b,c) __builtin_amdgcn_mfma_f32_16x16x32_f16((a),(b),(c),0,0,0)

// ---- main: 256 blocks (128 hgrp x 2 bgrp) x 512 threads ----
// Merged-region schedule (R19): midbar(s) -> [B(s) || A(s+1), shared h0new] ->
// B-epi -> (fc+endbar | sync) -> A-epi(xb) -> midbar(s+1).
// LDS: Wih1 64KB | Whh1 64KB | h-stage 2KB | whh0f chunk dbuf 2x8KB = 146KB
__global__ void __launch_bounds__(512, 1) k_main(
    const float* __restrict__ Wih0, const float* __restrict__ Whh0,
    const float* __restrict__ bih0, const float* __restrict__ bhh0,
    const float* __restrict__ Wih1, const float* __restrict__ Whh1,
    const float* __restrict__ bih1, const float* __restrict__ bhh1,
    const float* __restrict__ fc_w, const float* __restrict__ fc_b,
    char* __restrict__ ws, float* __restrict__ out)
{
  extern __shared__ char smem_[];
  f16* lds = (f16*)smem_;          // halves: [0,32768) Wih1 frags | [32768,65536) Whh1 frags
  f16* stage  = lds + 65536;       // 1024 halves: [128 local cols][8 units]
  f16* wstage = lds + 66560;       // 8192 halves: 2 bufs x 4096 (whh0f chunk staging)

  const int tid  = threadIdx.x;
  const int blk  = blockIdx.x;
  const int hgrp = blk & 127;
  const int bgrp = blk >> 7;
  const int j0   = hgrp << 3;
  const int l    = tid & 63;
  const int w8   = tid >> 6;
  const int q    = l >> 4;
  const int c16  = l & 15;
  const int lcol = (w8 << 4) + c16;
  const int bcol = (bgrp << 7) + lcol;

  // ---- pack Wih1, Whh1 slices into LDS as MFMA A-frags (once) ----
  {
    const float* srcs[2] = {Wih1, Whh1};
#pragma unroll
    for (int m = 0; m < 2; ++m){
#pragma unroll
      for (int fi = 0; fi < 8; ++fi){
        const int f = (w8 << 3) + fi;
        const int c = f >> 1, T = f & 1;
        const int r = c16;
        const int uu = (T << 2) + (r >> 2);
        const int g = r & 3;
        const float* src = srcs[m] + (((size_t)((g << 10) + j0 + uu)) << 10) + (c << 5) + (q << 3);
        float4 a = *(const float4*)src;
        float4 b = *(const float4*)(src + 4);
        f16x8 v;
        v[0]=(f16)a.x; v[1]=(f16)a.y; v[2]=(f16)a.z; v[3]=(f16)a.w;
        v[4]=(f16)b.x; v[5]=(f16)b.y; v[6]=(f16)b.z; v[7]=(f16)b.w;
        *(f16x8*)(lds + m*32768 + (f << 9) + (l << 3)) = v;
      }
    }
  }
  __syncthreads();

  // ---- per-lane constants (units q and q+4) ----
  float bias0t[2][4], bias1t[2][4], wi0t[2][4];
#pragma unroll
  for (int t = 0; t < 2; ++t){
    const int uu = j0 + q + t*4;
#pragma unroll
    for (int g = 0; g < 4; ++g){
      int row = (g << 10) + uu;
      bias0t[t][g] = bih0[row] + bhh0[row];
      bias1t[t][g] = bih1[row] + bhh1[row];
      wi0t[t][g]   = Wih0[row];
    }
  }
  const float fcw0 = fc_w[j0 + q] * 1.25f;
  const float fcw1 = fc_w[j0 + q + 4] * 1.25f;
  const float fcb  = fc_b[0];

  const int base_h = (q << 11) + (bcol << 3);

  f16* H0 = (f16*)(ws + H0_OFF);
  f16* H1 = (f16*)(ws + H1_OFF);
  const f16* whh0f = (const f16*)(ws + WHH0F_OFF) + ((size_t)hgrp << 15);
  const float* seq = (const float*)(ws + SEQ_OFF);
  float* y_acc = (float*)(ws + YACC_OFF);
  unsigned* flagsH = (unsigned*)(ws + FLAG_OFF) + bgrp*4096;   // 128 flags x 128B per half

  // ---- whh0f resident in registers (8 chunks x 16B/thread) ----
  u32x4 wreg[8];
#pragma unroll
  for (int ch = 0; ch < 8; ++ch)
    wreg[ch] = *(const u32x4*)(whh0f + ((size_t)ch << 12) + (tid << 3));

  float c0[2] = {0,0}, c1[2] = {0,0};
  unsigned ep = 0;

  // ---- prologue: A(0) with h0=0 -> gates = bias + wi0*x; publish h0 buf1 ----
  {
    float xb = seq[bcol];
#pragma unroll
    for (int t = 0; t < 2; ++t){
      float pi = bias0t[t][0] + wi0t[t][0]*xb;
      float pf = bias0t[t][1] + wi0t[t][1]*xb;
      float pg = bias0t[t][2] + wi0t[t][2]*xb;
      float po = bias0t[t][3] + wi0t[t][3]*xb;
      c0[t] = sigf(pi)*thf(pg);
      float h0n = sigf(po)*thf(c0[t]);
      stage[(lcol << 3) + q + t*4] = (f16)h0n;
    }
  }
  __syncthreads();
  if (tid < 128){
    u32x4 v = ((const u32x4*)stage)[tid];
    st_dwordx4_sc((char*)(H0 + 262144 + (hgrp << 11) + (bgrp << 10)) + tid*16, v);
  }
  ++ep; gbar(flagsH, ep, tid, hgrp, true);   // midbar(0)

#pragma unroll 1
  for (int s = 0; s < 107; ++s){
    const int p = s & 1;
    const bool doA = (s < 106);
    const f16* hb0 = H0 + (p^1)*262144 + base_h;   // h0new(s): shared B + A(s+1) operand
    const f16* hb1 = H1 + p*262144 + base_h;       // h1(s-1)

    // ========= merged region: B(s) [128 MFMA] || A(s+1) [64 MFMA], shared X0 =========
    f16x8 X0[2][4], X1[2][4];
    f32x4 accB0 = (f32x4){0,0,0,0}, accB1 = (f32x4){0,0,0,0};
    f32x4 accA0 = (f32x4){0,0,0,0}, accA1 = (f32x4){0,0,0,0};
#define LDX(B, CB) { _Pragma("unroll") for (int i = 0; i < 4; ++i){ const int c = (CB)+i; \
      X0[B][i] = *(const f16x8*)(hb0 + c*8192); \
      X1[B][i] = *(const f16x8*)(hb1 + c*8192); } }
#define MMW(B, CH) { const f16* wsb = wstage + (((CH)&1) << 12) + (l << 3); \
      _Pragma("unroll") for (int i = 0; i < 4; ++i){ \
      f16x8 wf0 = *(const f16x8*)(wsb + ((2*i  ) << 9)); \
      f16x8 wf1 = *(const f16x8*)(wsb + ((2*i+1) << 9)); \
      accA0 = MFMA16(wf0, X0[B][i], accA0); \
      accA1 = MFMA16(wf1, X0[B][i], accA1); } }
#define MMB(B, CB) { _Pragma("unroll") for (int i = 0; i < 4; ++i){ const int c = (CB)+i; \
      f16x8 wa0 = *(const f16x8*)(lds + ((2*c  ) << 9) + (l << 3)); \
      f16x8 wa1 = *(const f16x8*)(lds + ((2*c+1) << 9) + (l << 3)); \
      f16x8 wb0 = *(const f16x8*)(lds + 32768 + ((2*c  ) << 9) + (l << 3)); \
      f16x8 wb1 = *(const f16x8*)(lds + 32768 + ((2*c+1) << 9) + (l << 3)); \
      accB0 = MFMA16(wa0, X0[B][i], accB0); \
      accB0 = MFMA16(wb0, X1[B][i], accB0); \
      accB1 = MFMA16(wa1, X0[B][i], accB1); \
      accB1 = MFMA16(wb1, X1[B][i], accB1); } }
    LDX(0, 0) LDX(1, 4)
    *(u32x4*)(wstage + (tid << 3)) = wreg[0];
    __syncthreads();
#pragma unroll
    for (int ch = 0; ch < 8; ++ch){
      if (ch < 7) *(u32x4*)(wstage + (((ch+1)&1) << 12) + (tid << 3)) = wreg[ch+1];
      if (doA) MMW(ch&1, ch)
      MMB(ch&1, ch*4)
      if (ch < 6) LDX(ch&1, (ch+2)*4)
      if (ch < 7) __syncthreads();
    }
#undef LDX
#undef MMW
#undef MMB

    // ---- B epilogue: h1n, publish h1[p^1] ----
    float h1n[2];
    {
      f32x4 at[2] = {accB0, accB1};
#pragma unroll
      for (int t = 0; t < 2; ++t){
        float pi = at[t][0] + bias1t[t][0];
        float pf = at[t][1] + bias1t[t][1];
        float pg = at[t][2] + bias1t[t][2];
        float po = at[t][3] + bias1t[t][3];
        c1[t]  = sigf(pf)*c1[t] + sigf(pi)*thf(pg);
        h1n[t] = sigf(po)*thf(c1[t]);
        stage[(lcol << 3) + q + t*4] = (f16)h1n[t];
      }
    }
    __syncthreads();
    if (tid < 128){
      u32x4 v = ((const u32x4*)stage)[tid];
      st_dwordx4_sc((char*)(H1 + (p^1)*262144 + (hgrp << 11) + (bgrp << 10)) + tid*16, v);
    }

    // ---- fc + endbar (decoder), else local sync to protect stage ----
    if (s >= 83){
      const int tau = s - 83;
      uint2 fk = tf2x32(0u, 42u, 0u, (unsigned)tau);
      unsigned n0 = ((unsigned)bcol << 10) + (unsigned)(j0 + q);
      unsigned n1 = n0 + 4u;
      float v = (drop_keep(fk, n0) ? h1n[0]*fcw0 : 0.f)
              + (drop_keep(fk, n1) ? h1n[1]*fcw1 : 0.f);
      v += __shfl_xor(v, 16, 64);
      v += __shfl_xor(v, 32, 64);
      if (q == 0) atomicAdd(y_acc + (tau << 8) + bcol, v);
      ++ep; gbar(flagsH, ep, tid, hgrp, false);   // endbar(s), NO inv
    } else {
      __syncthreads();
    }

    // ---- A(s+1) epilogue: xb, gates from accA, publish h0[p]; midbar(s+1) ----
    if (doA){
      const int s1 = s + 1;
      float xb;
      if (s1 < 84){
        xb = seq[(s1 << 8) + bcol];
      } else {
        const int tp = s1 - 84;
        float yp = fcb + __uint_as_float(ld_dword_sc(y_acc + (tp << 8) + bcol));
        if (hgrp == 0 && q == 0) out[bcol*24 + tp] = yp;
        xb = yp;
      }
      f32x4 at[2] = {accA0, accA1};
#pragma unroll
      for (int t = 0; t < 2; ++t){
        float pi = at[t][0] + bias0t[t][0] + wi0t[t][0]*xb;
        float pf = at[t][1] + bias0t[t][1] + wi0t[t][1]*xb;
        float pg = at[t][2] + bias0t[t][2] + wi0t[t][2]*xb;
        float po = at[t][3] + bias0t[t][3] + wi0t[t][3]*xb;
        c0[t]  = sigf(pf)*c0[t] + sigf(pi)*thf(pg);
        float h0n = sigf(po)*thf(c0[t]);
        stage[(lcol << 3) + q + t*4] = (f16)h0n;
      }
      __syncthreads();
      if (tid < 128){
        u32x4 v = ((const u32x4*)stage)[tid];
        st_dwordx4_sc((char*)(H0 + p*262144 + (hgrp << 11) + (bgrp << 10)) + tid*16, v);
      }
      ++ep; gbar(flagsH, ep, tid, hgrp, true);    // midbar(s+1) WITH inv
    }
  }

  // tail: y_23 (after endbar(106); LLC-coherent read)
  if (hgrp == 0 && q == 0)
    out[bcol*24 + 23] = fcb + __uint_as_float(ld_dword_sc(y_acc + (23 << 8) + bcol));
}

extern "C" void kernel_launch(void* const* d_in, const int* in_sizes, int n_in,
                              void* d_out, int out_size, void* d_ws, size_t ws_size,
                              hipStream_t stream)
{
  const float* x    = (const float*)d_in[0];
  const float* cw   = (const float*)d_in[1];
  const float* cb   = (const float*)d_in[2];
  const float* Wih0 = (const float*)d_in[3];
  const float* Whh0 = (const float*)d_in[4];
  const float* bih0 = (const float*)d_in[5];
  const float* bhh0 = (const float*)d_in[6];
  const float* Wih1 = (const float*)d_in[7];
  const float* Whh1 = (const float*)d_in[8];
  const float* bih1 = (const float*)d_in[9];
  const float* bhh1 = (const float*)d_in[10];
  const float* fc_w = (const float*)d_in[11];
  const float* fc_b = (const float*)d_in[12];
  float* out = (float*)d_out;
  char*  ws  = (char*)d_ws;

  hipLaunchKernelGGL(k_init, dim3(1040), dim3(256), 0, stream,
                     (uint4*)(ws + H0_OFF), (uint4*)(ws + YACC_OFF), (uint4*)(ws + FLAG_OFF));
  hipLaunchKernelGGL(k_seq,  dim3(84), dim3(256), 0, stream, x, cw, cb, (float*)(ws + SEQ_OFF));
  hipLaunchKernelGGL(k_wpack, dim3(128), dim3(512), 0, stream, Whh0, (f16*)(ws + WHH0F_OFF));
  hipLaunchKernelGGL(k_main, dim3(256), dim3(512), 149504, stream,
                     Wih0, Whh0, bih0, bhh0, Wih1, Whh1, bih1, bhh1,
                     fc_w, fc_b, ws, out);
}

// Round 21
// 2680.768 us; speedup vs baseline: 2.1186x; 1.0452x over previous
//
#include <hip/hip_runtime.h>
#include <stdint.h>

typedef _Float16 f16;
typedef f16  f16x8 __attribute__((ext_vector_type(8)));
typedef float f32x4 __attribute__((ext_vector_type(4)));
typedef unsigned u32x4 __attribute__((ext_vector_type(4)));

// ---------------- ws layout (byte offsets) ----------------
// H0/H1: 2 bufs x [k/8][b][8] f16 (fp16-only h, 512KB per buf)
// WHH0F: fp16 MFMA A-frags of Whh0, [hgrp128][frag64][lane64][8] = 8 MB
// SEQ [84][256] f32 | YACC [24][256] f32 | FLAG 2 halves x 128 x 128B
#define H0_OFF    0u
#define H1_OFF    2097152u
#define WHH0F_OFF 4194304u
#define SEQ_OFF   12582912u
#define YACC_OFF  12668928u
#define FLAG_OFF  12693504u

__device__ __forceinline__ unsigned rotl32(unsigned x, int d){ return (x<<d)|(x>>(32-d)); }

// Threefry-2x32, 20 rounds, exactly JAX's key schedule. (bit-exact, proven R1-R20)
__device__ __forceinline__ uint2 tf2x32(unsigned k0, unsigned k1, unsigned x0, unsigned x1){
  unsigned kx = k0 ^ k1 ^ 0x1BD11BDAu;
  x0 += k0; x1 += k1;
#define TFR(r) { x0 += x1; x1 = rotl32(x1,(r)); x1 ^= x0; }
  TFR(13) TFR(15) TFR(26) TFR(6)  x0 += k1; x1 += kx + 1u;
  TFR(17) TFR(29) TFR(16) TFR(24) x0 += kx; x1 += k0 + 2u;
  TFR(13) TFR(15) TFR(26) TFR(6)  x0 += k0; x1 += k1 + 3u;
  TFR(17) TFR(29) TFR(16) TFR(24) x0 += k1; x1 += kx + 4u;
  TFR(13) TFR(15) TFR(26) TFR(6)  x0 += kx; x1 += k0 + 5u;
#undef TFR
  return make_uint2(x0, x1);
}

__device__ __forceinline__ bool drop_keep(uint2 fk, unsigned n){
  uint2 o = tf2x32(fk.x, fk.y, 0u, n);
  unsigned bits = o.x ^ o.y;
  float u = __uint_as_float((bits >> 9) | 0x3f800000u) - 1.0f;
  return u < 0.8f;
}

__device__ __forceinline__ float sigf(float x){ return 1.0f/(1.0f + __expf(-x)); }
__device__ __forceinline__ float thf(float x){ return 1.0f - 2.0f/(__expf(2.0f*x) + 1.0f); }

// ---- LLC-coherent accessors (proven R4-R20) ----
__device__ __forceinline__ void st_dword_sc(void* p, unsigned v){
  asm volatile("global_store_dword %0, %1, off sc0 sc1" :: "v"(p), "v"(v) : "memory");
}
__device__ __forceinline__ void st_dwordx4_sc(void* p, u32x4 v){
  asm volatile("global_store_dwordx4 %0, %1, off sc0 sc1" :: "v"(p), "v"(v) : "memory");
}
__device__ __forceinline__ unsigned ld_dword_sc(const void* p){
  unsigned r;
  asm volatile("global_load_dword %0, %1, off sc0 sc1\n\ts_waitcnt vmcnt(0)"
               : "=v"(r) : "v"(p) : "memory");
  return r;
}

// FLAT per-half barrier (R20) with EARLY inv: the L2-invalidate is issued right
// after our own arrival (pre-barrier state already drained; all publications are
// sc write-through, poll loads are sc/L2-bypassing -> no stale line can re-enter
// L2 before poll-exit), so the inv walk overlaps the arrival wait instead of
// serializing after it.
__device__ __forceinline__ void gbar(unsigned* flagsH, unsigned e,
                                     int tid, int lblk, bool inv){
  asm volatile("s_waitcnt vmcnt(0)" ::: "memory");
  __syncthreads();
  if (tid == 0) st_dword_sc(flagsH + lblk*32, e);
  if (inv) __builtin_amdgcn_fence(__ATOMIC_ACQUIRE, "agent");   // early inv, overlaps poll
  if (tid < 128){
    unsigned* f = flagsH + tid*32;
    while (ld_dword_sc(f) < e) __builtin_amdgcn_s_sleep(1);
  }
  __syncthreads();
  __builtin_amdgcn_sched_barrier(0);
}

// ---- prep: zero h buffers + y_acc + flags ----
__global__ void k_init(uint4* __restrict__ hz, uint4* __restrict__ yz, uint4* __restrict__ fz){
  unsigned i = blockIdx.x*256u + threadIdx.x;
  if (i < 262144u){ hz[i] = uint4{0,0,0,0}; }
  else if (i < 263680u){ yz[i - 262144u] = uint4{0,0,0,0}; }
  else if (i < 265728u){ fz[i - 263680u] = uint4{0,0,0,0}; }
}

// ---- prep: conv1d(pad1,k3) + relu + maxpool2 -> seq[84][256] ----
__global__ void k_seq(const float* __restrict__ x, const float* __restrict__ cw,
                      const float* __restrict__ cb, float* __restrict__ seq){
  const int q = blockIdx.x;
  const int b = threadIdx.x;
  float best = -1e30f;
#pragma unroll
  for (int ssub = 0; ssub < 2; ++ssub){
    int p = 2*q + ssub;
    float acc = cb[0];
#pragma unroll
    for (int k = 0; k < 3; ++k){
      int t = p - 1 + k;
      if (t >= 0 && t < 168){
        const float* xp = x + ((size_t)b*192 + t)*8;
#pragma unroll
        for (int i = 0; i < 8; ++i) acc = fmaf(xp[i], cw[i*3 + k], acc);
      }
    }
    acc  = fmaxf(acc, 0.0f);
    best = fmaxf(best, acc);
  }
  seq[(q<<8) + b] = best;
}

// ---- prep: pack Whh0 (fp32 [4096][1024]) into fp16 MFMA A-frags per hgrp ----
__global__ void __launch_bounds__(512) k_wpack(const float* __restrict__ W, f16* __restrict__ dst){
  const int hgrp = blockIdx.x;       // 0..127
  const int tid = threadIdx.x;
  const int l   = tid & 63;
  const int w   = tid >> 6;          // 0..7
  const int j0  = hgrp << 3;
#pragma unroll
  for (int fi = 0; fi < 8; ++fi){
    const int f = (w << 3) + fi;     // 0..63
    const int c = f >> 1, T = f & 1;
    const int r = l & 15;
    const int u = (T << 2) + (r >> 2);
    const int g = r & 3;
    const float* src = W + (((size_t)((g << 10) + j0 + u)) << 10) + (c << 5) + ((l >> 4) << 3);
    float4 a = *(const float4*)src;
    float4 b = *(const float4*)(src + 4);
    f16x8 v;
    v[0]=(f16)a.x; v[1]=(f16)a.y; v[2]=(f16)a.z; v[3]=(f16)a.w;
    v[4]=(f16)b.x; v[5]=(f16)b.y; v[6]=(f16)b.z; v[7]=(f16)b.w;
    *(f16x8*)(dst + ((size_t)hgrp << 15) + (f << 9) + (l << 3)) = v;
  }
}

#define MFMA16(a,b,c) __builtin_amdgcn_mfma_f32_16x16x32_f16((a),(b),(c),0,0,0)

// ---- main: 256 blocks (128 hgrp x 2 bgrp) x 512 threads ----
// Merged-region schedule (R19): midbar(s) -> [B(s) || A(s+1), shared h0new] ->
// B-epi -> (fc+endbar | sync) -> A-epi(xb) -> midbar(s+1).
// LDS: Wih1 64KB | Whh1 64KB | h-stage 2KB | whh0f chunk dbuf 2x8KB = 146KB
__global__ void __launch_bounds__(512, 1) k_main(
    const float* __restrict__ Wih0, const float* __restrict__ Whh0,
    const float* __restrict__ bih0, const float* __restrict__ bhh0,
    const float* __restrict__ Wih1, const float* __restrict__ Whh1,
    const float* __restrict__ bih1, const float* __restrict__ bhh1,
    const float* __restrict__ fc_w, const float* __restrict__ fc_b,
    char* __restrict__ ws, float* __restrict__ out)
{
  extern __shared__ char smem_[];
  f16* lds = (f16*)smem_;          // halves: [0,32768) Wih1 frags | [32768,65536) Whh1 frags
  f16* stage  = lds + 65536;       // 1024 halves: [128 local cols][8 units]
  f16* wstage = lds + 66560;       // 8192 halves: 2 bufs x 4096 (whh0f chunk staging)

  const int tid  = threadIdx.x;
  const int blk  = blockIdx.x;
  const int hgrp = blk & 127;
  const int bgrp = blk >> 7;
  const int j0   = hgrp << 3;
  const int l    = tid & 63;
  const int w8   = tid >> 6;
  const int q    = l >> 4;
  const int c16  = l & 15;
  const int lcol = (w8 << 4) + c16;
  const int bcol = (bgrp << 7) + lcol;

  // ---- pack Wih1, Whh1 slices into LDS as MFMA A-frags (once) ----
  {
    const float* srcs[2] = {Wih1, Whh1};
#pragma unroll
    for (int m = 0; m < 2; ++m){
#pragma unroll
      for (int fi = 0; fi < 8; ++fi){
        const int f = (w8 << 3) + fi;
        const int c = f >> 1, T = f & 1;
        const int r = c16;
        const int uu = (T << 2) + (r >> 2);
        const int g = r & 3;
        const float* src = srcs[m] + (((size_t)((g << 10) + j0 + uu)) << 10) + (c << 5) + (q << 3);
        float4 a = *(const float4*)src;
        float4 b = *(const float4*)(src + 4);
        f16x8 v;
        v[0]=(f16)a.x; v[1]=(f16)a.y; v[2]=(f16)a.z; v[3]=(f16)a.w;
        v[4]=(f16)b.x; v[5]=(f16)b.y; v[6]=(f16)b.z; v[7]=(f16)b.w;
        *(f16x8*)(lds + m*32768 + (f << 9) + (l << 3)) = v;
      }
    }
  }
  __syncthreads();

  // ---- per-lane constants (units q and q+4) ----
  float bias0t[2][4], bias1t[2][4], wi0t[2][4];
#pragma unroll
  for (int t = 0; t < 2; ++t){
    const int uu = j0 + q + t*4;
#pragma unroll
    for (int g = 0; g < 4; ++g){
      int row = (g << 10) + uu;
      bias0t[t][g] = bih0[row] + bhh0[row];
      bias1t[t][g] = bih1[row] + bhh1[row];
      wi0t[t][g]   = Wih0[row];
    }
  }
  const float fcw0 = fc_w[j0 + q] * 1.25f;
  const float fcw1 = fc_w[j0 + q + 4] * 1.25f;
  const float fcb  = fc_b[0];

  const int base_h = (q << 11) + (bcol << 3);

  f16* H0 = (f16*)(ws + H0_OFF);
  f16* H1 = (f16*)(ws + H1_OFF);
  const f16* whh0f = (const f16*)(ws + WHH0F_OFF) + ((size_t)hgrp << 15);
  const float* seq = (const float*)(ws + SEQ_OFF);
  float* y_acc = (float*)(ws + YACC_OFF);
  unsigned* flagsH = (unsigned*)(ws + FLAG_OFF) + bgrp*4096;   // 128 flags x 128B per half

  // ---- whh0f resident in registers (8 chunks x 16B/thread) ----
  u32x4 wreg[8];
#pragma unroll
  for (int ch = 0; ch < 8; ++ch)
    wreg[ch] = *(const u32x4*)(whh0f + ((size_t)ch << 12) + (tid << 3));

  float c0[2] = {0,0}, c1[2] = {0,0};
  unsigned ep = 0;

  // ---- prologue: A(0) with h0=0 -> gates = bias + wi0*x; publish h0 buf1 ----
  {
    float xb = seq[bcol];
#pragma unroll
    for (int t = 0; t < 2; ++t){
      float pi = bias0t[t][0] + wi0t[t][0]*xb;
      float pf = bias0t[t][1] + wi0t[t][1]*xb;
      float pg = bias0t[t][2] + wi0t[t][2]*xb;
      float po = bias0t[t][3] + wi0t[t][3]*xb;
      c0[t] = sigf(pi)*thf(pg);
      float h0n = sigf(po)*thf(c0[t]);
      stage[(lcol << 3) + q + t*4] = (f16)h0n;
    }
  }
  __syncthreads();
  if (tid < 128){
    u32x4 v = ((const u32x4*)stage)[tid];
    st_dwordx4_sc((char*)(H0 + 262144 + (hgrp << 11) + (bgrp << 10)) + tid*16, v);
  }
  ++ep; gbar(flagsH, ep, tid, hgrp, true);   // midbar(0)

#pragma unroll 1
  for (int s = 0; s < 107; ++s){
    const int p = s & 1;
    const bool doA = (s < 106);
    const f16* hb0 = H0 + (p^1)*262144 + base_h;   // h0new(s): shared B + A(s+1) operand
    const f16* hb1 = H1 + p*262144 + base_h;       // h1(s-1)

    // ========= merged region: B(s) [128 MFMA] || A(s+1) [64 MFMA], shared X0 =========
    f16x8 X0[2][4], X1[2][4];
    f32x4 accB0 = (f32x4){0,0,0,0}, accB1 = (f32x4){0,0,0,0};
    f32x4 accA0 = (f32x4){0,0,0,0}, accA1 = (f32x4){0,0,0,0};
#define LDX(B, CB) { _Pragma("unroll") for (int i = 0; i < 4; ++i){ const int c = (CB)+i; \
      X0[B][i] = *(const f16x8*)(hb0 + c*8192); \
      X1[B][i] = *(const f16x8*)(hb1 + c*8192); } }
#define MMW(B, CH) { const f16* wsb = wstage + (((CH)&1) << 12) + (l << 3); \
      _Pragma("unroll") for (int i = 0; i < 4; ++i){ \
      f16x8 wf0 = *(const f16x8*)(wsb + ((2*i  ) << 9)); \
      f16x8 wf1 = *(const f16x8*)(wsb + ((2*i+1) << 9)); \
      accA0 = MFMA16(wf0, X0[B][i], accA0); \
      accA1 = MFMA16(wf1, X0[B][i], accA1); } }
#define MMB(B, CB) { _Pragma("unroll") for (int i = 0; i < 4; ++i){ const int c = (CB)+i; \
      f16x8 wa0 = *(const f16x8*)(lds + ((2*c  ) << 9) + (l << 3)); \
      f16x8 wa1 = *(const f16x8*)(lds + ((2*c+1) << 9) + (l << 3)); \
      f16x8 wb0 = *(const f16x8*)(lds + 32768 + ((2*c  ) << 9) + (l << 3)); \
      f16x8 wb1 = *(const f16x8*)(lds + 32768 + ((2*c+1) << 9) + (l << 3)); \
      accB0 = MFMA16(wa0, X0[B][i], accB0); \
      accB0 = MFMA16(wb0, X1[B][i], accB0); \
      accB1 = MFMA16(wa1, X0[B][i], accB1); \
      accB1 = MFMA16(wb1, X1[B][i], accB1); } }
    LDX(0, 0) LDX(1, 4)
    *(u32x4*)(wstage + (tid << 3)) = wreg[0];
    __syncthreads();
#pragma unroll
    for (int ch = 0; ch < 8; ++ch){
      if (ch < 7) *(u32x4*)(wstage + (((ch+1)&1) << 12) + (tid << 3)) = wreg[ch+1];
      if (doA) MMW(ch&1, ch)
      MMB(ch&1, ch*4)
      if (ch < 6) LDX(ch&1, (ch+2)*4)
      if (ch < 7) __syncthreads();
    }
#undef LDX
#undef MMW
#undef MMB

    // ---- B epilogue: h1n, publish h1[p^1] ----
    float h1n[2];
    {
      f32x4 at[2] = {accB0, accB1};
#pragma unroll
      for (int t = 0; t < 2; ++t){
        float pi = at[t][0] + bias1t[t][0];
        float pf = at[t][1] + bias1t[t][1];
        float pg = at[t][2] + bias1t[t][2];
        float po = at[t][3] + bias1t[t][3];
        c1[t]  = sigf(pf)*c1[t] + sigf(pi)*thf(pg);
        h1n[t] = sigf(po)*thf(c1[t]);
        stage[(lcol << 3) + q + t*4] = (f16)h1n[t];
      }
    }
    __syncthreads();
    if (tid < 128){
      u32x4 v = ((const u32x4*)stage)[tid];
      st_dwordx4_sc((char*)(H1 + (p^1)*262144 + (hgrp << 11) + (bgrp << 10)) + tid*16, v);
    }

    // ---- fc + endbar (decoder), else local sync to protect stage ----
    if (s >= 83){
      const int tau = s - 83;
      uint2 fk = tf2x32(0u, 42u, 0u, (unsigned)tau);
      unsigned n0 = ((unsigned)bcol << 10) + (unsigned)(j0 + q);
      unsigned n1 = n0 + 4u;
      float v = (drop_keep(fk, n0) ? h1n[0]*fcw0 : 0.f)
              + (drop_keep(fk, n1) ? h1n[1]*fcw1 : 0.f);
      v += __shfl_xor(v, 16, 64);
      v += __shfl_xor(v, 32, 64);
      if (q == 0) atomicAdd(y_acc + (tau << 8) + bcol, v);
      ++ep; gbar(flagsH, ep, tid, hgrp, false);   // endbar(s), NO inv
    } else {
      __syncthreads();
    }

    // ---- A(s+1) epilogue: xb, gates from accA, publish h0[p]; midbar(s+1) ----
    if (doA){
      const int s1 = s + 1;
      float xb;
      if (s1 < 84){
        xb = seq[(s1 << 8) + bcol];
      } else {
        const int tp = s1 - 84;
        float yp = fcb + __uint_as_float(ld_dword_sc(y_acc + (tp << 8) + bcol));
        if (hgrp == 0 && q == 0) out[bcol*24 + tp] = yp;
        xb = yp;
      }
      f32x4 at[2] = {accA0, accA1};
#pragma unroll
      for (int t = 0; t < 2; ++t){
        float pi = at[t][0] + bias0t[t][0] + wi0t[t][0]*xb;
        float pf = at[t][1] + bias0t[t][1] + wi0t[t][1]*xb;
        float pg = at[t][2] + bias0t[t][2] + wi0t[t][2]*xb;
        float po = at[t][3] + bias0t[t][3] + wi0t[t][3]*xb;
        c0[t]  = sigf(pf)*c0[t] + sigf(pi)*thf(pg);
        float h0n = sigf(po)*thf(c0[t]);
        stage[(lcol << 3) + q + t*4] = (f16)h0n;
      }
      __syncthreads();
      if (tid < 128){
        u32x4 v = ((const u32x4*)stage)[tid];
        st_dwordx4_sc((char*)(H0 + p*262144 + (hgrp << 11) + (bgrp << 10)) + tid*16, v);
      }
      ++ep; gbar(flagsH, ep, tid, hgrp, true);    // midbar(s+1) WITH (early) inv
    }
  }

  // tail: y_23 (after endbar(106); LLC-coherent read)
  if (hgrp == 0 && q == 0)
    out[bcol*24 + 23] = fcb + __uint_as_float(ld_dword_sc(y_acc + (23 << 8) + bcol));
}

extern "C" void kernel_launch(void* const* d_in, const int* in_sizes, int n_in,
                              void* d_out, int out_size, void* d_ws, size_t ws_size,
                              hipStream_t stream)
{
  const float* x    = (const float*)d_in[0];
  const float* cw   = (const float*)d_in[1];
  const float* cb   = (const float*)d_in[2];
  const float* Wih0 = (const float*)d_in[3];
  const float* Whh0 = (const float*)d_in[4];
  const float* bih0 = (const float*)d_in[5];
  const float* bhh0 = (const float*)d_in[6];
  const float* Wih1 = (const float*)d_in[7];
  const float* Whh1 = (const float*)d_in[8];
  const float* bih1 = (const float*)d_in[9];
  const float* bhh1 = (const float*)d_in[10];
  const float* fc_w = (const float*)d_in[11];
  const float* fc_b = (const float*)d_in[12];
  float* out = (float*)d_out;
  char*  ws  = (char*)d_ws;

  hipLaunchKernelGGL(k_init, dim3(1040), dim3(256), 0, stream,
                     (uint4*)(ws + H0_OFF), (uint4*)(ws + YACC_OFF), (uint4*)(ws + FLAG_OFF));
  hipLaunchKernelGGL(k_seq,  dim3(84), dim3(256), 0, stream, x, cw, cb, (float*)(ws + SEQ_OFF));
  hipLaunchKernelGGL(k_wpack, dim3(128), dim3(512), 0, stream, Whh0, (f16*)(ws + WHH0F_OFF));
  hipLaunchKernelGGL(k_main, dim3(256), dim3(512), 149504, stream,
                     Wih0, Whh0, bih0, bhh0, Wih1, Whh1, bih1, bhh1,
                     fc_w, fc_b, ws, out);
}

// Round 22
// 2623.048 us; speedup vs baseline: 2.1653x; 1.0220x over previous
//
#include <hip/hip_runtime.h>
#include <stdint.h>

typedef _Float16 f16;
typedef f16  f16x8 __attribute__((ext_vector_type(8)));
typedef float f32x4 __attribute__((ext_vector_type(4)));
typedef unsigned u32x4 __attribute__((ext_vector_type(4)));

// ---------------- ws layout (byte offsets) ----------------
// H0/H1: 2 bufs x [k/8][b][8] f16 (fp16-only h, 512KB per buf region = 1MB each)
// YSLOT: 8 slots x [24 tau][256 col] f32 (hierarchical fc accumulators) 192KB
// SEQ [84][256] f32 | FLAG 2 halves x 128 x 128B
#define H0_OFF    0u
#define H1_OFF    1048576u
#define YSLOT_OFF 2097152u
#define SEQ_OFF   2293760u
#define FLAG_OFF  2379776u

__device__ __forceinline__ unsigned rotl32(unsigned x, int d){ return (x<<d)|(x>>(32-d)); }

// Threefry-2x32, 20 rounds, exactly JAX's key schedule. (bit-exact, proven R1-R21)
__device__ __forceinline__ uint2 tf2x32(unsigned k0, unsigned k1, unsigned x0, unsigned x1){
  unsigned kx = k0 ^ k1 ^ 0x1BD11BDAu;
  x0 += k0; x1 += k1;
#define TFR(r) { x0 += x1; x1 = rotl32(x1,(r)); x1 ^= x0; }
  TFR(13) TFR(15) TFR(26) TFR(6)  x0 += k1; x1 += kx + 1u;
  TFR(17) TFR(29) TFR(16) TFR(24) x0 += kx; x1 += k0 + 2u;
  TFR(13) TFR(15) TFR(26) TFR(6)  x0 += k0; x1 += k1 + 3u;
  TFR(17) TFR(29) TFR(16) TFR(24) x0 += k1; x1 += kx + 4u;
  TFR(13) TFR(15) TFR(26) TFR(6)  x0 += kx; x1 += k0 + 5u;
#undef TFR
  return make_uint2(x0, x1);
}

__device__ __forceinline__ bool drop_keep(uint2 fk, unsigned n){
  uint2 o = tf2x32(fk.x, fk.y, 0u, n);
  unsigned bits = o.x ^ o.y;
  float u = __uint_as_float((bits >> 9) | 0x3f800000u) - 1.0f;
  return u < 0.8f;
}

__device__ __forceinline__ float sigf(float x){ return 1.0f/(1.0f + __expf(-x)); }
__device__ __forceinline__ float thf(float x){ return 1.0f - 2.0f/(__expf(2.0f*x) + 1.0f); }

// ---- LLC-coherent accessors (proven R4-R21) ----
__device__ __forceinline__ void st_dword_sc(void* p, unsigned v){
  asm volatile("global_store_dword %0, %1, off sc0 sc1" :: "v"(p), "v"(v) : "memory");
}
__device__ __forceinline__ void st_dwordx4_sc(void* p, u32x4 v){
  asm volatile("global_store_dwordx4 %0, %1, off sc0 sc1" :: "v"(p), "v"(v) : "memory");
}
__device__ __forceinline__ unsigned ld_dword_sc(const void* p){
  unsigned r;
  asm volatile("global_load_dword %0, %1, off sc0 sc1\n\ts_waitcnt vmcnt(0)"
               : "=v"(r) : "v"(p) : "memory");
  return r;
}
// async sc load (no internal wait); caller batches a single vmcnt(0).
__device__ __forceinline__ void ld_sc_async(unsigned& d, const void* p){
  asm volatile("global_load_dword %0, %1, off sc0 sc1" : "=&v"(d) : "v"(p));
}

// FLAT per-half barrier with EARLY inv (proven R20/R21).
__device__ __forceinline__ void gbar(unsigned* flagsH, unsigned e,
                                     int tid, int lblk, bool inv){
  asm volatile("s_waitcnt vmcnt(0)" ::: "memory");
  __syncthreads();
  if (tid == 0) st_dword_sc(flagsH + lblk*32, e);
  if (inv) __builtin_amdgcn_fence(__ATOMIC_ACQUIRE, "agent");   // early inv, overlaps poll
  if (tid < 128){
    unsigned* f = flagsH + tid*32;
    while (ld_dword_sc(f) < e) __builtin_amdgcn_s_sleep(1);
  }
  __syncthreads();
  __builtin_amdgcn_sched_barrier(0);
}

// ---- prep: zero H1 buf0 + y slots + flags (all that needs zeros) ----
__global__ void k_init(uint4* __restrict__ hz, uint4* __restrict__ yz, uint4* __restrict__ fz){
  unsigned i = blockIdx.x*256u + threadIdx.x;
  if (i < 32768u){ hz[i] = uint4{0,0,0,0}; }
  else if (i < 45056u){ yz[i - 32768u] = uint4{0,0,0,0}; }
  else if (i < 47104u){ fz[i - 45056u] = uint4{0,0,0,0}; }
}

// ---- prep: conv1d(pad1,k3) + relu + maxpool2 -> seq[84][256] ----
__global__ void k_seq(const float* __restrict__ x, const float* __restrict__ cw,
                      const float* __restrict__ cb, float* __restrict__ seq){
  const int q = blockIdx.x;
  const int b = threadIdx.x;
  float best = -1e30f;
#pragma unroll
  for (int ssub = 0; ssub < 2; ++ssub){
    int p = 2*q + ssub;
    float acc = cb[0];
#pragma unroll
    for (int k = 0; k < 3; ++k){
      int t = p - 1 + k;
      if (t >= 0 && t < 168){
        const float* xp = x + ((size_t)b*192 + t)*8;
#pragma unroll
        for (int i = 0; i < 8; ++i) acc = fmaf(xp[i], cw[i*3 + k], acc);
      }
    }
    acc  = fmaxf(acc, 0.0f);
    best = fmaxf(best, acc);
  }
  seq[(q<<8) + b] = best;
}

#define MFMA16(a,b,c) __builtin_amdgcn_mfma_f32_16x16x32_f16((a),(b),(c),0,0,0)

// ---- main: 256 blocks (128 hgrp x 2 bgrp) x 512 threads ----
// Merged-region schedule (R19): midbar(s) -> [B(s) || A(s+1), shared h0new] ->
// B-epi -> (fc+endbar | sync) -> A-epi(xb) -> midbar(s+1).
// Whh0 frags packed DIRECTLY into registers (no wpack kernel, bit-identical).
// fc reduction: 8 hierarchical atomic slots (16-way contention) + batched 8-load sum.
// LDS: Wih1 64KB | Whh1 64KB | h-stage 2KB | whh0f chunk dbuf 2x8KB = 146KB
__global__ void __launch_bounds__(512, 1) k_main(
    const float* __restrict__ Wih0, const float* __restrict__ Whh0,
    const float* __restrict__ bih0, const float* __restrict__ bhh0,
    const float* __restrict__ Wih1, const float* __restrict__ Whh1,
    const float* __restrict__ bih1, const float* __restrict__ bhh1,
    const float* __restrict__ fc_w, const float* __restrict__ fc_b,
    char* __restrict__ ws, float* __restrict__ out)
{
  extern __shared__ char smem_[];
  f16* lds = (f16*)smem_;          // halves: [0,32768) Wih1 frags | [32768,65536) Whh1 frags
  f16* stage  = lds + 65536;       // 1024 halves: [128 local cols][8 units]
  f16* wstage = lds + 66560;       // 8192 halves: 2 bufs x 4096 (whh0f chunk staging)

  const int tid  = threadIdx.x;
  const int blk  = blockIdx.x;
  const int hgrp = blk & 127;
  const int bgrp = blk >> 7;
  const int j0   = hgrp << 3;
  const int l    = tid & 63;
  const int w8   = tid >> 6;
  const int q    = l >> 4;
  const int c16  = l & 15;
  const int lcol = (w8 << 4) + c16;
  const int bcol = (bgrp << 7) + lcol;

  // ---- pack Wih1, Whh1 slices into LDS as MFMA A-frags (once) ----
  {
    const float* srcs[2] = {Wih1, Whh1};
#pragma unroll
    for (int m = 0; m < 2; ++m){
#pragma unroll
      for (int fi = 0; fi < 8; ++fi){
        const int f = (w8 << 3) + fi;
        const int c = f >> 1, T = f & 1;
        const int r = c16;
        const int uu = (T << 2) + (r >> 2);
        const int g = r & 3;
        const float* src = srcs[m] + (((size_t)((g << 10) + j0 + uu)) << 10) + (c << 5) + (q << 3);
        float4 a = *(const float4*)src;
        float4 b = *(const float4*)(src + 4);
        f16x8 v;
        v[0]=(f16)a.x; v[1]=(f16)a.y; v[2]=(f16)a.z; v[3]=(f16)a.w;
        v[4]=(f16)b.x; v[5]=(f16)b.y; v[6]=(f16)b.z; v[7]=(f16)b.w;
        *(f16x8*)(lds + m*32768 + (f << 9) + (l << 3)) = v;
      }
    }
  }
  __syncthreads();

  // ---- whh0f packed DIRECTLY into registers (8 chunks; frag f = ch*8 + w8) ----
  u32x4 wreg[8];
#pragma unroll
  for (int ch = 0; ch < 8; ++ch){
    const int f = (ch << 3) + w8;
    const int c = f >> 1, T = f & 1;
    const int uu = (T << 2) + (c16 >> 2);
    const int g = c16 & 3;
    const float* src = Whh0 + (((size_t)((g << 10) + j0 + uu)) << 10) + (c << 5) + (q << 3);
    float4 a = *(const float4*)src;
    float4 b = *(const float4*)(src + 4);
    f16x8 v;
    v[0]=(f16)a.x; v[1]=(f16)a.y; v[2]=(f16)a.z; v[3]=(f16)a.w;
    v[4]=(f16)b.x; v[5]=(f16)b.y; v[6]=(f16)b.z; v[7]=(f16)b.w;
    wreg[ch] = __builtin_bit_cast(u32x4, v);
  }

  // ---- per-lane constants (units q and q+4) ----
  float bias0t[2][4], bias1t[2][4], wi0t[2][4];
#pragma unroll
  for (int t = 0; t < 2; ++t){
    const int uu = j0 + q + t*4;
#pragma unroll
    for (int g = 0; g < 4; ++g){
      int row = (g << 10) + uu;
      bias0t[t][g] = bih0[row] + bhh0[row];
      bias1t[t][g] = bih1[row] + bhh1[row];
      wi0t[t][g]   = Wih0[row];
    }
  }
  const float fcw0 = fc_w[j0 + q] * 1.25f;
  const float fcw1 = fc_w[j0 + q + 4] * 1.25f;
  const float fcb  = fc_b[0];

  const int base_h = (q << 11) + (bcol << 3);

  f16* H0 = (f16*)(ws + H0_OFF);
  f16* H1 = (f16*)(ws + H1_OFF);
  const float* seq = (const float*)(ws + SEQ_OFF);
  float* y_slot = (float*)(ws + YSLOT_OFF);     // [8 slot][24 tau][256 col]
  unsigned* flagsH = (unsigned*)(ws + FLAG_OFF) + bgrp*4096;

  float c0[2] = {0,0}, c1[2] = {0,0};
  unsigned ep = 0;

  // ---- prologue: A(0) with h0=0 -> gates = bias + wi0*x; publish h0 buf1 ----
  {
    float xb = seq[bcol];
#pragma unroll
    for (int t = 0; t < 2; ++t){
      float pi = bias0t[t][0] + wi0t[t][0]*xb;
      float pf = bias0t[t][1] + wi0t[t][1]*xb;
      float pg = bias0t[t][2] + wi0t[t][2]*xb;
      float po = bias0t[t][3] + wi0t[t][3]*xb;
      c0[t] = sigf(pi)*thf(pg);
      float h0n = sigf(po)*thf(c0[t]);
      stage[(lcol << 3) + q + t*4] = (f16)h0n;
    }
  }
  __syncthreads();
  if (tid < 128){
    u32x4 v = ((const u32x4*)stage)[tid];
    st_dwordx4_sc((char*)(H0 + 262144 + (hgrp << 11) + (bgrp << 10)) + tid*16, v);
  }
  ++ep; gbar(flagsH, ep, tid, hgrp, true);   // midbar(0)

#pragma unroll 1
  for (int s = 0; s < 107; ++s){
    const int p = s & 1;
    const bool doA = (s < 106);
    const f16* hb0 = H0 + (p^1)*262144 + base_h;   // h0new(s): shared B + A(s+1) operand
    const f16* hb1 = H1 + p*262144 + base_h;       // h1(s-1)

    // ========= merged region: B(s) [128 MFMA] || A(s+1) [64 MFMA], shared X0 =========
    f16x8 X0[2][4], X1[2][4];
    f32x4 accB0 = (f32x4){0,0,0,0}, accB1 = (f32x4){0,0,0,0};
    f32x4 accA0 = (f32x4){0,0,0,0}, accA1 = (f32x4){0,0,0,0};
#define LDX(B, CB) { _Pragma("unroll") for (int i = 0; i < 4; ++i){ const int c = (CB)+i; \
      X0[B][i] = *(const f16x8*)(hb0 + c*8192); \
      X1[B][i] = *(const f16x8*)(hb1 + c*8192); } }
#define MMW(B, CH) { const f16* wsb = wstage + (((CH)&1) << 12) + (l << 3); \
      _Pragma("unroll") for (int i = 0; i < 4; ++i){ \
      f16x8 wf0 = *(const f16x8*)(wsb + ((2*i  ) << 9)); \
      f16x8 wf1 = *(const f16x8*)(wsb + ((2*i+1) << 9)); \
      accA0 = MFMA16(wf0, X0[B][i], accA0); \
      accA1 = MFMA16(wf1, X0[B][i], accA1); } }
#define MMB(B, CB) { _Pragma("unroll") for (int i = 0; i < 4; ++i){ const int c = (CB)+i; \
      f16x8 wa0 = *(const f16x8*)(lds + ((2*c  ) << 9) + (l << 3)); \
      f16x8 wa1 = *(const f16x8*)(lds + ((2*c+1) << 9) + (l << 3)); \
      f16x8 wb0 = *(const f16x8*)(lds + 32768 + ((2*c  ) << 9) + (l << 3)); \
      f16x8 wb1 = *(const f16x8*)(lds + 32768 + ((2*c+1) << 9) + (l << 3)); \
      accB0 = MFMA16(wa0, X0[B][i], accB0); \
      accB0 = MFMA16(wb0, X1[B][i], accB0); \
      accB1 = MFMA16(wa1, X0[B][i], accB1); \
      accB1 = MFMA16(wb1, X1[B][i], accB1); } }
    LDX(0, 0) LDX(1, 4)
    *(u32x4*)(wstage + (tid << 3)) = wreg[0];
    __syncthreads();
#pragma unroll
    for (int ch = 0; ch < 8; ++ch){
      if (ch < 7) *(u32x4*)(wstage + (((ch+1)&1) << 12) + (tid << 3)) = wreg[ch+1];
      if (doA) MMW(ch&1, ch)
      MMB(ch&1, ch*4)
      if (ch < 6) LDX(ch&1, (ch+2)*4)
      if (ch < 7) __syncthreads();
    }
#undef LDX
#undef MMW
#undef MMB

    // ---- B epilogue: h1n, publish h1[p^1] ----
    float h1n[2];
    {
      f32x4 at[2] = {accB0, accB1};
#pragma unroll
      for (int t = 0; t < 2; ++t){
        float pi = at[t][0] + bias1t[t][0];
        float pf = at[t][1] + bias1t[t][1];
        float pg = at[t][2] + bias1t[t][2];
        float po = at[t][3] + bias1t[t][3];
        c1[t]  = sigf(pf)*c1[t] + sigf(pi)*thf(pg);
        h1n[t] = sigf(po)*thf(c1[t]);
        stage[(lcol << 3) + q + t*4] = (f16)h1n[t];
      }
    }
    __syncthreads();
    if (tid < 128){
      u32x4 v = ((const u32x4*)stage)[tid];
      st_dwordx4_sc((char*)(H1 + (p^1)*262144 + (hgrp << 11) + (bgrp << 10)) + tid*16, v);
    }

    // ---- fc (hierarchical slots) + endbar (decoder), else local sync ----
    if (s >= 83){
      const int tau = s - 83;
      uint2 fk = tf2x32(0u, 42u, 0u, (unsigned)tau);
      unsigned n0 = ((unsigned)bcol << 10) + (unsigned)(j0 + q);
      unsigned n1 = n0 + 4u;
      float v = (drop_keep(fk, n0) ? h1n[0]*fcw0 : 0.f)
              + (drop_keep(fk, n1) ? h1n[1]*fcw1 : 0.f);
      v += __shfl_xor(v, 16, 64);
      v += __shfl_xor(v, 32, 64);
      if (q == 0) atomicAdd(y_slot + ((hgrp & 7)*24 + tau)*256 + bcol, v);
      ++ep; gbar(flagsH, ep, tid, hgrp, false);   // endbar(s), NO inv
    } else {
      __syncthreads();
    }

    // ---- A(s+1) epilogue: xb, gates from accA, publish h0[p]; midbar(s+1) ----
    if (doA){
      const int s1 = s + 1;
      float xb;
      if (s1 < 84){
        xb = seq[(s1 << 8) + bcol];
      } else {
        const int tp = s1 - 84;
        const float* yb = y_slot + tp*256 + bcol;
        unsigned r[8];
#pragma unroll
        for (int m = 0; m < 8; ++m) ld_sc_async(r[m], yb + m*6144);
        asm volatile("s_waitcnt vmcnt(0)" ::: "memory");
        __builtin_amdgcn_sched_barrier(0);
        float yp = fcb;
#pragma unroll
        for (int m = 0; m < 8; ++m) yp += __uint_as_float(r[m]);
        if (hgrp == 0 && q == 0) out[bcol*24 + tp] = yp;
        xb = yp;
      }
      f32x4 at[2] = {accA0, accA1};
#pragma unroll
      for (int t = 0; t < 2; ++t){
        float pi = at[t][0] + bias0t[t][0] + wi0t[t][0]*xb;
        float pf = at[t][1] + bias0t[t][1] + wi0t[t][1]*xb;
        float pg = at[t][2] + bias0t[t][2] + wi0t[t][2]*xb;
        float po = at[t][3] + bias0t[t][3] + wi0t[t][3]*xb;
        c0[t]  = sigf(pf)*c0[t] + sigf(pi)*thf(pg);
        float h0n = sigf(po)*thf(c0[t]);
        stage[(lcol << 3) + q + t*4] = (f16)h0n;
      }
      __syncthreads();
      if (tid < 128){
        u32x4 v = ((const u32x4*)stage)[tid];
        st_dwordx4_sc((char*)(H0 + p*262144 + (hgrp << 11) + (bgrp << 10)) + tid*16, v);
      }
      ++ep; gbar(flagsH, ep, tid, hgrp, true);    // midbar(s+1) WITH (early) inv
    }
  }

  // tail: y_23 (after endbar(106); batched slot sum)
  if (hgrp == 0 && q == 0){
    const float* yb = y_slot + 23*256 + bcol;
    unsigned r[8];
#pragma unroll
    for (int m = 0; m < 8; ++m) ld_sc_async(r[m], yb + m*6144);
    asm volatile("s_waitcnt vmcnt(0)" ::: "memory");
    __builtin_amdgcn_sched_barrier(0);
    float yp = fcb;
#pragma unroll
    for (int m = 0; m < 8; ++m) yp += __uint_as_float(r[m]);
    out[bcol*24 + 23] = yp;
  }
}

extern "C" void kernel_launch(void* const* d_in, const int* in_sizes, int n_in,
                              void* d_out, int out_size, void* d_ws, size_t ws_size,
                              hipStream_t stream)
{
  const float* x    = (const float*)d_in[0];
  const float* cw   = (const float*)d_in[1];
  const float* cb   = (const float*)d_in[2];
  const float* Wih0 = (const float*)d_in[3];
  const float* Whh0 = (const float*)d_in[4];
  const float* bih0 = (const float*)d_in[5];
  const float* bhh0 = (const float*)d_in[6];
  const float* Wih1 = (const float*)d_in[7];
  const float* Whh1 = (const float*)d_in[8];
  const float* bih1 = (const float*)d_in[9];
  const float* bhh1 = (const float*)d_in[10];
  const float* fc_w = (const float*)d_in[11];
  const float* fc_b = (const float*)d_in[12];
  float* out = (float*)d_out;
  char*  ws  = (char*)d_ws;

  hipLaunchKernelGGL(k_init, dim3(184), dim3(256), 0, stream,
                     (uint4*)(ws + H1_OFF), (uint4*)(ws + YSLOT_OFF), (uint4*)(ws + FLAG_OFF));
  hipLaunchKernelGGL(k_seq,  dim3(84), dim3(256), 0, stream, x, cw, cb, (float*)(ws + SEQ_OFF));
  hipLaunchKernelGGL(k_main, dim3(256), dim3(512), 149504, stream,
                     Wih0, Whh0, bih0, bhh0, Wih1, Whh1, bih1, bhh1,
                     fc_w, fc_b, ws, out);
}